// Round 16
// baseline (289.566 us; speedup 1.0000x reference)
//
#include <hip/hip_runtime.h>
#include <hip/hip_fp16.h>
#include <math.h>

// Problem constants (fixed by reference)
#define S   8000     // L = 20*20*20
#define BB  2
#define CC  96
#define DI  192      // d_inner
#define NS  16       // d_state
#define RK  6        // dt_rank
#define GG  6        // B * 3 directions
#define NC  400      // scan chunks
#define LC  20       // chunk length
#define ND  38       // dt_rank + 2*d_state

typedef __attribute__((ext_vector_type(8))) short bf16x8;
typedef __attribute__((ext_vector_type(4))) float f32x4;
typedef __attribute__((ext_vector_type(2))) float f32x2;

__device__ __forceinline__ int pos_from_l(int dir, int l) {
  if (dir == 0) return l;
  int a  = l / 400;
  int r  = l - a * 400;
  int bq = r / 20;
  int cq = r - bq * 20;
  if (dir == 1) return cq * 400 + a * 20 + bq;
  return bq * 400 + cq * 20 + a;
}

__device__ __forceinline__ float silu(float z) {
  return z / (1.f + __expf(-z));
}
__device__ __forceinline__ unsigned short f2bf(float x) {
  unsigned int u = __float_as_uint(x);
  u += 0x7FFFu + ((u >> 16) & 1u);
  return (unsigned short)(u >> 16);
}
__device__ __forceinline__ float bf2f(unsigned short h) {
  return __uint_as_float((unsigned int)h << 16);
}
__device__ __forceinline__ float h2f_bits(unsigned short h) {
  __half hh = *reinterpret_cast<__half*>(&h);
  return __half2float(hh);
}
__device__ __forceinline__ unsigned short f2h_bits(float x) {
  __half hh = __float2half(x);
  return *reinterpret_cast<unsigned short*>(&hh);
}
__device__ __forceinline__ float quad_sum(float x) {
  x += __int_as_float(__builtin_amdgcn_update_dpp(0, __float_as_int(x), 0xB1, 0xF, 0xF, true));
  x += __int_as_float(__builtin_amdgcn_update_dpp(0, __float_as_int(x), 0x4E, 0xF, 0xF, true));
  return x;
}

// ======== fused LayerNorm + bf16 MFMA GEMM over K=CC=96 ==================
template <int ACT, bool DOUBLE, bool OUTBF16>
__global__ __launch_bounds__(256) void k_lnmfma(const float* __restrict__ Xsrc,
    const float* __restrict__ lnw, const float* __restrict__ lnb,
    const float* __restrict__ mlnw, const float* __restrict__ mlnb,
    const float* __restrict__ Bw, const float* __restrict__ bias,
    void* __restrict__ Cout, int M, int N) {
  __shared__ float Xf[64][97];
  __shared__ unsigned short Al[64][104];
  __shared__ unsigned short Bl[96][104];
  int tid = threadIdx.x;
  int m0 = blockIdx.x * 64, n0 = blockIdx.y * 96;
  int b = m0 / S, pos0 = m0 - b * S;
  for (int idx = tid; idx < 64 * 96; idx += 256) {
    int row = idx & 63, c = idx >> 6;
    Xf[row][c] = Xsrc[((size_t)b * CC + c) * S + pos0 + row];
  }
  for (int idx = tid; idx < 96 * 24; idx += 256) {
    int bn = idx / 24, kq = idx - bn * 24;
    int n = n0 + bn;
    float4 v = make_float4(0.f, 0.f, 0.f, 0.f);
    if (n < N) v = *(const float4*)&Bw[(size_t)n * 96 + kq * 4];
    unsigned short* dst = &Bl[bn][kq * 4];
    dst[0] = f2bf(v.x); dst[1] = f2bf(v.y);
    dst[2] = f2bf(v.z); dst[3] = f2bf(v.w);
  }
  __syncthreads();
  {
    int row = tid >> 2, part = tid & 3;
    const float* xr = &Xf[row][part * 24];
    float s1 = 0.f, s2 = 0.f;
#pragma unroll
    for (int i = 0; i < 24; ++i) { float v = xr[i]; s1 += v; s2 += v * v; }
    s1 = quad_sum(s1); s2 = quad_sum(s2);
    float u = s1 * (1.f / 96.f);
    float var = s2 * (1.f / 96.f) - u * u;
    float rstd = rsqrtf(var + 1e-6f);
    if (DOUBLE) {
      float t1 = 0.f, t2 = 0.f;
#pragma unroll
      for (int i = 0; i < 24; ++i) {
        int c = part * 24 + i;
        float y1 = fmaf(lnw[c], (xr[i] - u) * rstd, lnb[c]);
        t1 += y1; t2 += y1 * y1;
      }
      t1 = quad_sum(t1); t2 = quad_sum(t2);
      float u2 = t1 * (1.f / 96.f);
      float var2 = t2 * (1.f / 96.f) - u2 * u2;
      float rstd2 = rsqrtf(var2 + 1e-5f);
#pragma unroll
      for (int i = 0; i < 24; ++i) {
        int c = part * 24 + i;
        float y1 = fmaf(lnw[c], (xr[i] - u) * rstd, lnb[c]);
        Al[row][c] = f2bf(fmaf(mlnw[c], (y1 - u2) * rstd2, mlnb[c]));
      }
    } else {
#pragma unroll
      for (int i = 0; i < 24; ++i) {
        int c = part * 24 + i;
        Al[row][c] = f2bf(fmaf(lnw[c], (xr[i] - u) * rstd, lnb[c]));
      }
    }
  }
  __syncthreads();
  int wid = tid >> 6, lane = tid & 63;
  int wr = wid >> 1, wc = wid & 1;
  int l16 = lane & 15, lk = (lane >> 4) * 8;
  f32x4 acc[2][3];
#pragma unroll
  for (int i = 0; i < 2; ++i)
#pragma unroll
    for (int j = 0; j < 3; ++j) acc[i][j] = (f32x4){0.f, 0.f, 0.f, 0.f};
#pragma unroll
  for (int kc = 0; kc < 96; kc += 32) {
    bf16x8 af[2], bfr[3];
#pragma unroll
    for (int i = 0; i < 2; ++i)
      af[i] = *(const bf16x8*)&Al[wr * 32 + i * 16 + l16][kc + lk];
#pragma unroll
    for (int j = 0; j < 3; ++j)
      bfr[j] = *(const bf16x8*)&Bl[wc * 48 + j * 16 + l16][kc + lk];
#pragma unroll
    for (int i = 0; i < 2; ++i)
#pragma unroll
      for (int j = 0; j < 3; ++j)
        acc[i][j] = __builtin_amdgcn_mfma_f32_16x16x32_bf16(
            af[i], bfr[j], acc[i][j], 0, 0, 0);
  }
#pragma unroll
  for (int i = 0; i < 2; ++i) {
#pragma unroll
    for (int j = 0; j < 3; ++j) {
#pragma unroll
      for (int v = 0; v < 4; ++v) {
        int m = m0 + wr * 32 + i * 16 + (lane >> 4) * 4 + v;
        int n = n0 + wc * 48 + j * 16 + l16;
        if (n < N) {
          float val = acc[i][j][v];
          val += bias ? bias[n] : 0.f;
          if (ACT == 1) val = 0.5f * val * (1.f + erff(val * 0.70710678118654752f));
          if (OUTBF16) ((unsigned short*)Cout)[(size_t)m * N + n] = f2bf(val);
          else         ((float*)Cout)[(size_t)m * N + n] = val;
        }
      }
    }
  }
}

// -------- bf16 MFMA GEMM --------------------------------------------------
#define BKP 40
template <int ACT, bool BIAS, bool RESID, bool OUT_BCS, bool GATEA, bool ABF16>
__global__ __launch_bounds__(256) void k_mfma(const void* __restrict__ Ap,
    const float* __restrict__ Bw, const float* __restrict__ bias,
    const float* __restrict__ resid, const unsigned short* __restrict__ XZg,
    float* __restrict__ Cmat, int M, int N, int K) {
  __shared__ unsigned short Al[64][BKP];
  __shared__ unsigned short Bl[96][BKP];
  int tid = threadIdx.x;
  int m0 = blockIdx.x * 64, n0 = blockIdx.y * 96;
  int wid = tid >> 6, lane = tid & 63;
  int wr = wid >> 1, wc = wid & 1;
  int l16 = lane & 15, lk = (lane >> 4) * 8;
  f32x4 acc[2][3];
#pragma unroll
  for (int i = 0; i < 2; ++i)
#pragma unroll
    for (int j = 0; j < 3; ++j) acc[i][j] = (f32x4){0.f, 0.f, 0.f, 0.f};

  for (int kk = 0; kk < K; kk += 32) {
    if (ABF16) {
      int row = tid >> 2, kq = tid & 3;
      int m = m0 + row;
      const unsigned short* As = (const unsigned short*)Ap;
      uint4 v = *(const uint4*)&As[(size_t)m * K + kk + kq * 8];
      if (GATEA) {
        unsigned short* pv = (unsigned short*)&v;
        int bb = m / S, ll = m - bb * S;
        int j = kk + kq * 8;
        int dir = j / DI; int e0 = j - dir * DI;
        int p = pos_from_l(dir, ll);
        uint4 zv = *(const uint4*)&XZg[((size_t)bb * S + p) * 384 + DI + e0];
        const unsigned short* zp = (const unsigned short*)&zv;
#pragma unroll
        for (int q = 0; q < 8; ++q)
          pv[q] = f2bf(bf2f(pv[q]) * silu(bf2f(zp[q])));
      }
      *(uint4*)&Al[row][kq * 8] = v;
    } else {
#pragma unroll
      for (int i = 0; i < 2; ++i) {
        int idx = tid + i * 256;
        int row = idx >> 3, kq = idx & 7;
        int m = m0 + row;
        const float* Af = (const float*)Ap;
        float4 v = *(const float4*)&Af[(size_t)m * K + kk + kq * 4];
        unsigned short* dst = &Al[row][kq * 4];
        dst[0] = f2bf(v.x); dst[1] = f2bf(v.y);
        dst[2] = f2bf(v.z); dst[3] = f2bf(v.w);
      }
    }
#pragma unroll
    for (int i = 0; i < 3; ++i) {
      int idx = tid + i * 256;
      int bn = idx >> 3, kq = idx & 7;
      int n = n0 + bn;
      float4 v = make_float4(0.f, 0.f, 0.f, 0.f);
      if (n < N) v = *(const float4*)&Bw[(size_t)n * K + kk + kq * 4];
      unsigned short* dst = &Bl[bn][kq * 4];
      dst[0] = f2bf(v.x); dst[1] = f2bf(v.y);
      dst[2] = f2bf(v.z); dst[3] = f2bf(v.w);
    }
    __syncthreads();
    bf16x8 af[2], bfr[3];
#pragma unroll
    for (int i = 0; i < 2; ++i)
      af[i] = *(const bf16x8*)&Al[wr * 32 + i * 16 + l16][lk];
#pragma unroll
    for (int j = 0; j < 3; ++j)
      bfr[j] = *(const bf16x8*)&Bl[wc * 48 + j * 16 + l16][lk];
#pragma unroll
    for (int i = 0; i < 2; ++i)
#pragma unroll
      for (int j = 0; j < 3; ++j)
        acc[i][j] = __builtin_amdgcn_mfma_f32_16x16x32_bf16(
            af[i], bfr[j], acc[i][j], 0, 0, 0);
    __syncthreads();
  }
#pragma unroll
  for (int i = 0; i < 2; ++i) {
#pragma unroll
    for (int j = 0; j < 3; ++j) {
#pragma unroll
      for (int v = 0; v < 4; ++v) {
        int m = m0 + wr * 32 + i * 16 + (lane >> 4) * 4 + v;
        int n = n0 + wc * 48 + j * 16 + l16;
        if (n < N) {
          float val = acc[i][j][v];
          if (BIAS) val += bias[n];
          if (ACT == 1) val = 0.5f * val * (1.f + erff(val * 0.70710678118654752f));
          if (RESID || OUT_BCS) {
            int bb = m / S, pp = m - bb * S;
            size_t oidx = ((size_t)bb * CC + n) * S + pp;
            if (RESID) val += resid[oidx];
            if (OUT_BCS) { Cmat[oidx] = val; continue; }
          }
          Cmat[(size_t)m * N + n] = val;
        }
      }
    }
  }
}

// ------- causal depthwise conv(4) + SiLU, bf16 in/out, 4 ch/thread -------
__global__ __launch_bounds__(256) void k_conv(const unsigned short* __restrict__ XZb,
    const float* __restrict__ cw, const float* __restrict__ cb,
    unsigned short* __restrict__ xcb) {
  int t = blockIdx.x * blockDim.x + threadIdx.x;
  if (t >= GG * S * 48) return;
  int q = t % 48; int gl = t / 48; int l = gl % S; int g = gl / S;
  int e0 = q * 4;
  int b = g / 3, dir = g - (g / 3) * 3;
  float cwv[4][4];
#pragma unroll
  for (int i = 0; i < 4; ++i)
    *(float4*)cwv[i] = *(const float4*)&cw[(e0 + i) * 4];
  float4 acc = *(const float4*)&cb[e0];
#pragma unroll
  for (int k = 0; k < 4; ++k) {
    int ls = l + k - 3;
    if (ls >= 0) {
      int p = pos_from_l(dir, ls);
      uint2 xz = *(const uint2*)&XZb[((size_t)b * S + p) * 384 + e0];
      const unsigned short* xp = (const unsigned short*)&xz;
      acc.x = fmaf(cwv[0][k], bf2f(xp[0]), acc.x);
      acc.y = fmaf(cwv[1][k], bf2f(xp[1]), acc.y);
      acc.z = fmaf(cwv[2][k], bf2f(xp[2]), acc.z);
      acc.w = fmaf(cwv[3][k], bf2f(xp[3]), acc.w);
    }
  }
  unsigned short o[4];
  o[0] = f2bf(acc.x * (1.f / (1.f + __expf(-acc.x))));
  o[1] = f2bf(acc.y * (1.f / (1.f + __expf(-acc.y))));
  o[2] = f2bf(acc.z * (1.f / (1.f + __expf(-acc.z))));
  o[3] = f2bf(acc.w * (1.f / (1.f + __expf(-acc.w))));
  *(uint2*)&xcb[(size_t)gl * DI + e0] = *(uint2*)o;
}

// ------- dt/r precompute (x4 per thread) -> packed (fp16 dt | fp16 r) ----
__global__ __launch_bounds__(256) void k_dtr(const float* __restrict__ xdbl,
    const float* __restrict__ Wdt, const float* __restrict__ bdt,
    const float* __restrict__ A_log, unsigned int* __restrict__ dr) {
  int t = blockIdx.x * blockDim.x + threadIdx.x;
  if (t >= GG * S * 48) return;
  int q = t % 48; int row = t / 48;
  int e0 = q * 4;
  const float* xr = xdbl + (size_t)row * ND;
  float r0 = xr[0], r1 = xr[1], r2 = xr[2], r3 = xr[3], r4 = xr[4], r5 = xr[5];
  unsigned int out[4];
#pragma unroll
  for (int i = 0; i < 4; ++i) {
    int e = e0 + i;
    const float* wp = &Wdt[e * RK];
    float a = bdt[e];
    a = fmaf(wp[0], r0, a); a = fmaf(wp[1], r1, a); a = fmaf(wp[2], r2, a);
    a = fmaf(wp[3], r3, a); a = fmaf(wp[4], r4, a); a = fmaf(wp[5], r5, a);
    float d = fmaxf(a, 0.f) + __logf(1.f + __expf(-fabsf(a)));
    float base = -__expf(A_log[e * NS]);
    out[i] = (unsigned int)f2h_bits(d) | ((unsigned int)f2h_bits(__expf(d * base)) << 16);
  }
  *(uint4*)&dr[(size_t)row * DI + e0] = *(uint4*)out;
}

// ======== scanA2: local recurrence + partial y + T, 16 states/thread =====
__global__ __launch_bounds__(192) void k_scanA2(const unsigned short* __restrict__ xcb,
    const unsigned int* __restrict__ dr, const float* __restrict__ xdbl,
    const float* __restrict__ A_log, const float* __restrict__ Dp,
    float* __restrict__ PA, float* __restrict__ EA,
    unsigned short* __restrict__ Tb, unsigned short* __restrict__ ygb) {
  __shared__ float sBC[LC][32];
  int c = blockIdx.x, g = blockIdx.y;
  int tid = threadIdx.x;
  int e = tid;
  {
    const float* src = xdbl + ((size_t)g * S + c * LC) * ND + RK;
    for (int i = tid; i < LC * 32; i += 192) {
      int row = i >> 5, col = i & 31;
      sBC[row][col] = src[(size_t)row * ND + col];
    }
  }
  float base = -__expf(A_log[e * NS]);
  bool fast = true;
#pragma unroll
  for (int s = 1; s < NS; ++s) {
    float aes = -__expf(A_log[e * NS + s]);
    fast = fast && (fabsf(aes / base - (float)(s + 1)) < 1e-3f);
  }
  float dpe = Dp[e];
  f32x2 h2[8];
#pragma unroll
  for (int k = 0; k < 8; ++k) h2[k] = (f32x2){0.f, 0.f};
  float T = 0.f;
  size_t sbase = ((size_t)g * S + c * LC) * DI + e;
  const unsigned short* xp = xcb + sbase;
  const unsigned int* drp = dr + sbase;
  unsigned short* Tp = Tb + sbase;
  int b = g / 3, dir = g - (g / 3) * 3;
  unsigned short* yo = ygb + ((size_t)b * S + c * LC) * 576 + dir * DI + e;
  __syncthreads();
  if (fast) {
    unsigned short xb[2][4];
    unsigned int dv[2][4];
#pragma unroll
    for (int j = 0; j < 4; ++j) {
      xb[0][j] = xp[(size_t)j * DI];
      dv[0][j] = drp[(size_t)j * DI];
    }
#pragma unroll
    for (int blk = 0; blk < 5; ++blk) {
      int cb = blk & 1, nb = cb ^ 1;
      if (blk < 4) {
#pragma unroll
        for (int j = 0; j < 4; ++j) {
          xb[nb][j] = xp[(size_t)(blk * 4 + 4 + j) * DI];
          dv[nb][j] = drp[(size_t)(blk * 4 + 4 + j) * DI];
        }
      }
#pragma unroll
      for (int j = 0; j < 4; ++j) {
        int l = blk * 4 + j;
        float xv = bf2f(xb[cb][j]);
        unsigned int v = dv[cb][j];
        float d = h2f_bits((unsigned short)(v & 0xffff));
        float r = h2f_bits((unsigned short)(v >> 16));
        T += d;
        Tp[(size_t)l * DI] = f2h_bits(T);
        float w = d * xv;
        float r2 = r * r, r4 = r2 * r2, r8 = r4 * r4;
        f32x2 r2v = {r2, r2}, r4v = {r4, r4}, r8v = {r8, r8};
        f32x2 m0 = {r, r2};
        f32x2 m1 = m0 * r2v, m2 = m0 * r4v, m3 = m1 * r4v;
        f32x2 m4 = m0 * r8v, m5 = m1 * r8v, m6 = m2 * r8v, m7 = m3 * r8v;
        f32x2 wv = {w, w};
        float4 Ba = *(const float4*)&sBC[l][0];
        float4 Bb = *(const float4*)&sBC[l][4];
        float4 Bc = *(const float4*)&sBC[l][8];
        float4 Bd = *(const float4*)&sBC[l][12];
        float4 Ca = *(const float4*)&sBC[l][16];
        float4 Cb2 = *(const float4*)&sBC[l][20];
        float4 Cc = *(const float4*)&sBC[l][24];
        float4 Cd = *(const float4*)&sBC[l][28];
        f32x2 ya = {xv * dpe, 0.f};
        h2[0] = m0 * h2[0] + wv * (f32x2){Ba.x, Ba.y}; ya += h2[0] * (f32x2){Ca.x, Ca.y};
        h2[1] = m1 * h2[1] + wv * (f32x2){Ba.z, Ba.w}; ya += h2[1] * (f32x2){Ca.z, Ca.w};
        h2[2] = m2 * h2[2] + wv * (f32x2){Bb.x, Bb.y}; ya += h2[2] * (f32x2){Cb2.x, Cb2.y};
        h2[3] = m3 * h2[3] + wv * (f32x2){Bb.z, Bb.w}; ya += h2[3] * (f32x2){Cb2.z, Cb2.w};
        h2[4] = m4 * h2[4] + wv * (f32x2){Bc.x, Bc.y}; ya += h2[4] * (f32x2){Cc.x, Cc.y};
        h2[5] = m5 * h2[5] + wv * (f32x2){Bc.z, Bc.w}; ya += h2[5] * (f32x2){Cc.z, Cc.w};
        h2[6] = m6 * h2[6] + wv * (f32x2){Bd.x, Bd.y}; ya += h2[6] * (f32x2){Cd.x, Cd.y};
        h2[7] = m7 * h2[7] + wv * (f32x2){Bd.z, Bd.w}; ya += h2[7] * (f32x2){Cd.z, Cd.w};
        yo[(size_t)l * 576] = f2bf(ya[0] + ya[1]);
      }
    }
  } else {
    float Aes[NS];
#pragma unroll
    for (int s = 0; s < NS; ++s) Aes[s] = -__expf(A_log[e * NS + s]);
#pragma unroll 1
    for (int l = 0; l < LC; ++l) {
      unsigned int v = drp[(size_t)l * DI];
      float d = h2f_bits((unsigned short)(v & 0xffff));
      float xv = bf2f(xp[(size_t)l * DI]);
      T += d;
      Tp[(size_t)l * DI] = f2h_bits(T);
      float w = d * xv;
      float y = xv * dpe;
#pragma unroll
      for (int s = 0; s < NS; ++s) {
        float q = __expf(d * Aes[s]);
        float hk = fmaf(q, h2[s >> 1][s & 1], w * sBC[l][s]);
        h2[s >> 1][s & 1] = hk;
        y = fmaf(hk, sBC[l][16 + s], y);
      }
      yo[(size_t)l * 576] = f2bf(y);
    }
  }
  float* pp = PA + (((size_t)g * NC + c) * DI + e) * NS;
  float* ep = EA + (((size_t)g * NC + c) * DI + e) * NS;
  float po[NS];
  if (fast) {
    float R = __expf(base * T);
    float R2 = R * R, R4 = R2 * R2, R8 = R4 * R4;
    po[0] = R; po[1] = R2; po[2] = R * R2; po[3] = R4;
    po[4] = R4 * R; po[5] = R4 * R2; po[6] = po[5] * R; po[7] = R8;
    po[8] = R8 * R; po[9] = R8 * R2; po[10] = po[9] * R; po[11] = R8 * R4;
    po[12] = po[11] * R; po[13] = po[11] * R2; po[14] = po[13] * R; po[15] = R8 * R8;
  } else {
#pragma unroll
    for (int s = 0; s < NS; ++s)
      po[s] = __expf(-__expf(A_log[e * NS + s]) * T);
  }
#pragma unroll
  for (int s = 0; s < NS; s += 4) {
    *(float4*)&pp[s] = make_float4(po[s], po[s+1], po[s+2], po[s+3]);
    *(float4*)&ep[s] = make_float4(h2[s>>1][0], h2[s>>1][1], h2[(s>>1)+1][0], h2[(s>>1)+1][1]);
  }
}

// inter-chunk sequential combine, 16-deep prefetch (Hin aliases PA)
__global__ __launch_bounds__(256) void k_scanB(const float* PA,
    const float* EA, float* Hin) {
  int idx = blockIdx.x * blockDim.x + threadIdx.x;
  if (idx >= GG * DI * NS) return;
  int g = idx / (DI * NS); int es = idx - g * (DI * NS);
  size_t stride = (size_t)DI * NS;
  size_t b0 = (size_t)g * NC * stride + es;
  float h = 0.f;
  for (int c0 = 0; c0 < NC; c0 += 16) {
    float p16[16], e16[16];
#pragma unroll
    for (int j = 0; j < 16; ++j) {
      size_t ix = b0 + (size_t)(c0 + j) * stride;
      p16[j] = PA[ix]; e16[j] = EA[ix];
    }
#pragma unroll
    for (int j = 0; j < 16; ++j) {
      size_t ix = b0 + (size_t)(c0 + j) * stride;
      Hin[ix] = h;
      h = fmaf(p16[j], h, e16[j]);
    }
  }
}

// ======== scanC2: correction pass y += C * R^(s+1) * h_in ================
__global__ __launch_bounds__(192) void k_scanC2(const unsigned short* __restrict__ Tb,
    const float* __restrict__ xdbl, const float* __restrict__ A_log,
    const float* __restrict__ Hin, unsigned short* __restrict__ ygb) {
  __shared__ float sC[LC][16];
  int c = blockIdx.x, g = blockIdx.y;
  int tid = threadIdx.x;
  int e = tid;
  {
    const float* src = xdbl + ((size_t)g * S + c * LC) * ND + RK + 16;
    for (int i = tid; i < LC * 16; i += 192) {
      int row = i >> 4, col = i & 15;
      sC[row][col] = src[(size_t)row * ND + col];
    }
  }
  float base = -__expf(A_log[e * NS]);
  bool fast = true;
#pragma unroll
  for (int s = 1; s < NS; ++s) {
    float aes = -__expf(A_log[e * NS + s]);
    fast = fast && (fabsf(aes / base - (float)(s + 1)) < 1e-3f);
  }
  const float* hp = Hin + (((size_t)g * NC + c) * DI + e) * NS;
  float4 hv0 = *(const float4*)(hp + 0);
  float4 hv1 = *(const float4*)(hp + 4);
  float4 hv2 = *(const float4*)(hp + 8);
  float4 hv3 = *(const float4*)(hp + 12);
  f32x2 hin[8] = {{hv0.x, hv0.y}, {hv0.z, hv0.w}, {hv1.x, hv1.y}, {hv1.z, hv1.w},
                  {hv2.x, hv2.y}, {hv2.z, hv2.w}, {hv3.x, hv3.y}, {hv3.z, hv3.w}};
  float hmag = fabsf(hv0.x) + fabsf(hv0.y) + fabsf(hv0.z) + fabsf(hv0.w) +
               fabsf(hv1.x) + fabsf(hv1.y) + fabsf(hv1.z) + fabsf(hv1.w) +
               fabsf(hv2.x) + fabsf(hv2.y) + fabsf(hv2.z) + fabsf(hv2.w) +
               fabsf(hv3.x) + fabsf(hv3.y) + fabsf(hv3.z) + fabsf(hv3.w);
  size_t sbase = ((size_t)g * S + c * LC) * DI + e;
  const unsigned short* Tp = Tb + sbase;
  int b = g / 3, dir = g - (g / 3) * 3;
  unsigned short* yo = ygb + ((size_t)b * S + c * LC) * 576 + dir * DI + e;
  __syncthreads();
  if (__builtin_amdgcn_ballot_w64(hmag != 0.f) == 0ull) return;
  if (fast) {
    unsigned short tb2[2][4], yb[2][4];
#pragma unroll
    for (int j = 0; j < 4; ++j) {
      tb2[0][j] = Tp[(size_t)j * DI];
      yb[0][j] = yo[(size_t)j * 576];
    }
#pragma unroll
    for (int blk = 0; blk < 5; ++blk) {
      int cb = blk & 1, nb = cb ^ 1;
      if (blk < 4) {
#pragma unroll
        for (int j = 0; j < 4; ++j) {
          tb2[nb][j] = Tp[(size_t)(blk * 4 + 4 + j) * DI];
          yb[nb][j] = yo[(size_t)(blk * 4 + 4 + j) * 576];
        }
      }
#pragma unroll
      for (int j = 0; j < 4; ++j) {
        int l = blk * 4 + j;
        float T = h2f_bits(tb2[cb][j]);
        float R = __expf(base * T);
        float R2 = R * R, R4 = R2 * R2, R8 = R4 * R4;
        f32x2 R2v = {R2, R2}, R4v = {R4, R4}, R8v = {R8, R8};
        f32x2 q0 = {R, R2};
        f32x2 q1 = q0 * R2v, q2 = q0 * R4v, q3 = q1 * R4v;
        f32x2 q4 = q0 * R8v, q5 = q1 * R8v, q6 = q2 * R8v, q7 = q3 * R8v;
        float4 Ca = *(const float4*)&sC[l][0];
        float4 Cb2 = *(const float4*)&sC[l][4];
        float4 Cc = *(const float4*)&sC[l][8];
        float4 Cd = *(const float4*)&sC[l][12];
        f32x2 ca = (hin[0] * q0) * (f32x2){Ca.x, Ca.y};
        ca += (hin[1] * q1) * (f32x2){Ca.z, Ca.w};
        ca += (hin[2] * q2) * (f32x2){Cb2.x, Cb2.y};
        ca += (hin[3] * q3) * (f32x2){Cb2.z, Cb2.w};
        ca += (hin[4] * q4) * (f32x2){Cc.x, Cc.y};
        ca += (hin[5] * q5) * (f32x2){Cc.z, Cc.w};
        ca += (hin[6] * q6) * (f32x2){Cd.x, Cd.y};
        ca += (hin[7] * q7) * (f32x2){Cd.z, Cd.w};
        float y = bf2f(yb[cb][j]) + ca[0] + ca[1];
        yo[(size_t)l * 576] = f2bf(y);
      }
    }
  } else {
    float Aes[NS];
#pragma unroll
    for (int s = 0; s < NS; ++s) Aes[s] = -__expf(A_log[e * NS + s]);
#pragma unroll 1
    for (int l = 0; l < LC; ++l) {
      float T = h2f_bits(Tp[(size_t)l * DI]);
      float y = bf2f(yo[(size_t)l * 576]);
#pragma unroll
      for (int s = 0; s < NS; ++s) {
        float W = __expf(Aes[s] * T);
        y = fmaf(hin[s >> 1][s & 1] * W, sC[l][s], y);
      }
      yo[(size_t)l * 576] = f2bf(y);
    }
  }
}

// ---------------- fold Wout into proj_w: Mcat[o, dir*192+e] --------------
__global__ __launch_bounds__(256) void k_foldW(const float* __restrict__ proj_w,
    const float* __restrict__ Wout, float* __restrict__ Mcat) {
  int t = blockIdx.x * blockDim.x + threadIdx.x;
  if (t >= CC * 576) return;
  int o = t / 576; int j = t - o * 576; int dir = j / DI; int e = j - dir * DI;
  float a = 0.f;
  for (int c2 = 0; c2 < CC; ++c2)
    a = fmaf(proj_w[o * 288 + dir * CC + c2], Wout[c2 * DI + e], a);
  Mcat[t] = a;
}

extern "C" void kernel_launch(void* const* d_in, const int* in_sizes, int n_in,
                              void* d_out, int out_size, void* d_ws, size_t ws_size,
                              hipStream_t stream) {
  const float* x      = (const float*)d_in[0];
  const float* ln_w   = (const float*)d_in[1];
  const float* ln_b   = (const float*)d_in[2];
  const float* mln_w  = (const float*)d_in[3];
  const float* mln_b  = (const float*)d_in[4];
  const float* Win    = (const float*)d_in[5];
  const float* conv_w = (const float*)d_in[6];
  const float* conv_b = (const float*)d_in[7];
  const float* Wx     = (const float*)d_in[8];
  const float* Wdt    = (const float*)d_in[9];
  const float* bdt    = (const float*)d_in[10];
  const float* A_log  = (const float*)d_in[11];
  const float* Dp     = (const float*)d_in[12];
  const float* Wout   = (const float*)d_in[13];
  const float* proj_w = (const float*)d_in[14];
  const float* proj_b = (const float*)d_in[15];
  const float* fc1_w  = (const float*)d_in[16];
  const float* fc1_b  = (const float*)d_in[17];
  const float* fc2_w  = (const float*)d_in[18];
  const float* fc2_b  = (const float*)d_in[19];

  float* ws = (float*)d_ws;
  size_t off = 0;
  float* ores = ws + off; off += (size_t)BB * S * CC;        // f32
  float* XZf  = ws + off; off += (size_t)BB * S * 384 / 2;   // bf16 (+h1 alias)
  float* xcf  = ws + off; off += (size_t)GG * S * DI / 2;    // bf16
  float* xdbl = ws + off; off += (size_t)GG * S * ND;        // f32
  float* drf  = ws + off; off += (size_t)GG * S * DI;        // packed u32
  float* Tf   = ws + off; off += (size_t)GG * S * DI / 2;    // fp16
  float* PA   = ws + off; off += (size_t)GG * NC * DI * NS;  // 7.37M fl
  float* EA   = ws + off; off += (size_t)GG * NC * DI * NS;  // 7.37M fl
  float* yg   = ws + off; off += (size_t)BB * S * 576 / 2;   // bf16
  float* Mcat = ws + off; off += (size_t)CC * 576;
  if (ws_size < off * sizeof(float)) return;                 // ~168 MB; guard
  float* Hin  = PA;
  unsigned short* XZb = (unsigned short*)XZf;
  unsigned short* xcb = (unsigned short*)xcf;
  unsigned int*   dr  = (unsigned int*)drf;
  unsigned short* Tb  = (unsigned short*)Tf;
  unsigned short* ygb = (unsigned short*)yg;
  unsigned short* h1  = (unsigned short*)XZf;

  k_lnmfma<0, true, true><<<dim3(BB * S / 64, 4), 256, 0, stream>>>(
      x, ln_w, ln_b, mln_w, mln_b, Win, nullptr, XZb, BB * S, 384);
  k_conv<<<(GG * S * 48 + 255) / 256, 256, 0, stream>>>(XZb, conv_w, conv_b, xcb);
  k_mfma<0, false, false, false, false, true>
      <<<dim3(GG * S / 64, 1), 256, 0, stream>>>(
      xcb, Wx, nullptr, nullptr, nullptr, xdbl, GG * S, ND, DI);
  k_dtr<<<(GG * S * 48 + 255) / 256, 256, 0, stream>>>(
      xdbl, Wdt, bdt, A_log, dr);
  k_scanA2<<<dim3(NC, GG), 192, 0, stream>>>(
      xcb, dr, xdbl, A_log, Dp, PA, EA, Tb, ygb);
  k_scanB<<<(GG * DI * NS + 255) / 256, 256, 0, stream>>>(PA, EA, Hin);
  k_scanC2<<<dim3(NC, GG), 192, 0, stream>>>(
      Tb, xdbl, A_log, Hin, ygb);
  k_foldW<<<(CC * 576 + 255) / 256, 256, 0, stream>>>(proj_w, Wout, Mcat);
  k_mfma<0, true, true, true, true, true>
      <<<dim3(BB * S / 64, 1), 256, 0, stream>>>(
      ygb, Mcat, proj_b, x, XZb, ores, BB * S, CC, 576);
  k_lnmfma<1, false, true><<<dim3(BB * S / 64, 4), 256, 0, stream>>>(
      ores, ln_w, ln_b, nullptr, nullptr, fc1_w, fc1_b, h1, BB * S, 384);
  k_mfma<0, true, true, true, false, true>
      <<<dim3(BB * S / 64, 1), 256, 0, stream>>>(
      h1, fc2_w, fc2_b, ores, nullptr, (float*)d_out, BB * S, CC, 384);
}

// Round 17
// 256.214 us; speedup vs baseline: 1.1302x; 1.1302x over previous
//
#include <hip/hip_runtime.h>
#include <hip/hip_fp16.h>
#include <math.h>

// Problem constants (fixed by reference)
#define S   8000     // L = 20*20*20
#define BB  2
#define CC  96
#define DI  192      // d_inner
#define NS  16       // d_state
#define RK  6        // dt_rank
#define GG  6        // B * 3 directions
#define NC  200      // scan chunks
#define LC  40       // chunk length
#define ND  38       // dt_rank + 2*d_state

typedef __attribute__((ext_vector_type(8))) short bf16x8;
typedef __attribute__((ext_vector_type(4))) float f32x4;
typedef __attribute__((ext_vector_type(2))) float f32x2;

__device__ __forceinline__ int pos_from_l(int dir, int l) {
  if (dir == 0) return l;
  int a  = l / 400;
  int r  = l - a * 400;
  int bq = r / 20;
  int cq = r - bq * 20;
  if (dir == 1) return cq * 400 + a * 20 + bq;
  return bq * 400 + cq * 20 + a;
}

__device__ __forceinline__ float silu(float z) {
  return z / (1.f + __expf(-z));
}
__device__ __forceinline__ unsigned short f2bf(float x) {
  unsigned int u = __float_as_uint(x);
  u += 0x7FFFu + ((u >> 16) & 1u);
  return (unsigned short)(u >> 16);
}
__device__ __forceinline__ float bf2f(unsigned short h) {
  return __uint_as_float((unsigned int)h << 16);
}
__device__ __forceinline__ float h2f_bits(unsigned short h) {
  __half hh = *reinterpret_cast<__half*>(&h);
  return __half2float(hh);
}
__device__ __forceinline__ unsigned short f2h_bits(float x) {
  __half hh = __float2half(x);
  return *reinterpret_cast<unsigned short*>(&hh);
}
__device__ __forceinline__ float quad_sum(float x) {
  x += __int_as_float(__builtin_amdgcn_update_dpp(0, __float_as_int(x), 0xB1, 0xF, 0xF, true));
  x += __int_as_float(__builtin_amdgcn_update_dpp(0, __float_as_int(x), 0x4E, 0xF, 0xF, true));
  return x;
}

// ======== fused LayerNorm + bf16 MFMA GEMM over K=CC=96 ==================
template <int ACT, bool DOUBLE, bool OUTBF16>
__global__ __launch_bounds__(256) void k_lnmfma(const float* __restrict__ Xsrc,
    const float* __restrict__ lnw, const float* __restrict__ lnb,
    const float* __restrict__ mlnw, const float* __restrict__ mlnb,
    const float* __restrict__ Bw, const float* __restrict__ bias,
    void* __restrict__ Cout, int M, int N) {
  __shared__ float Xf[64][97];
  __shared__ unsigned short Al[64][104];
  __shared__ unsigned short Bl[96][104];
  int tid = threadIdx.x;
  int m0 = blockIdx.x * 64, n0 = blockIdx.y * 96;
  int b = m0 / S, pos0 = m0 - b * S;
  for (int idx = tid; idx < 64 * 96; idx += 256) {
    int row = idx & 63, c = idx >> 6;
    Xf[row][c] = Xsrc[((size_t)b * CC + c) * S + pos0 + row];
  }
  for (int idx = tid; idx < 96 * 24; idx += 256) {
    int bn = idx / 24, kq = idx - bn * 24;
    int n = n0 + bn;
    float4 v = make_float4(0.f, 0.f, 0.f, 0.f);
    if (n < N) v = *(const float4*)&Bw[(size_t)n * 96 + kq * 4];
    unsigned short* dst = &Bl[bn][kq * 4];
    dst[0] = f2bf(v.x); dst[1] = f2bf(v.y);
    dst[2] = f2bf(v.z); dst[3] = f2bf(v.w);
  }
  __syncthreads();
  {
    int row = tid >> 2, part = tid & 3;
    const float* xr = &Xf[row][part * 24];
    float s1 = 0.f, s2 = 0.f;
#pragma unroll
    for (int i = 0; i < 24; ++i) { float v = xr[i]; s1 += v; s2 += v * v; }
    s1 = quad_sum(s1); s2 = quad_sum(s2);
    float u = s1 * (1.f / 96.f);
    float var = s2 * (1.f / 96.f) - u * u;
    float rstd = rsqrtf(var + 1e-6f);
    if (DOUBLE) {
      float t1 = 0.f, t2 = 0.f;
#pragma unroll
      for (int i = 0; i < 24; ++i) {
        int c = part * 24 + i;
        float y1 = fmaf(lnw[c], (xr[i] - u) * rstd, lnb[c]);
        t1 += y1; t2 += y1 * y1;
      }
      t1 = quad_sum(t1); t2 = quad_sum(t2);
      float u2 = t1 * (1.f / 96.f);
      float var2 = t2 * (1.f / 96.f) - u2 * u2;
      float rstd2 = rsqrtf(var2 + 1e-5f);
#pragma unroll
      for (int i = 0; i < 24; ++i) {
        int c = part * 24 + i;
        float y1 = fmaf(lnw[c], (xr[i] - u) * rstd, lnb[c]);
        Al[row][c] = f2bf(fmaf(mlnw[c], (y1 - u2) * rstd2, mlnb[c]));
      }
    } else {
#pragma unroll
      for (int i = 0; i < 24; ++i) {
        int c = part * 24 + i;
        Al[row][c] = f2bf(fmaf(lnw[c], (xr[i] - u) * rstd, lnb[c]));
      }
    }
  }
  __syncthreads();
  int wid = tid >> 6, lane = tid & 63;
  int wr = wid >> 1, wc = wid & 1;
  int l16 = lane & 15, lk = (lane >> 4) * 8;
  f32x4 acc[2][3];
#pragma unroll
  for (int i = 0; i < 2; ++i)
#pragma unroll
    for (int j = 0; j < 3; ++j) acc[i][j] = (f32x4){0.f, 0.f, 0.f, 0.f};
#pragma unroll
  for (int kc = 0; kc < 96; kc += 32) {
    bf16x8 af[2], bfr[3];
#pragma unroll
    for (int i = 0; i < 2; ++i)
      af[i] = *(const bf16x8*)&Al[wr * 32 + i * 16 + l16][kc + lk];
#pragma unroll
    for (int j = 0; j < 3; ++j)
      bfr[j] = *(const bf16x8*)&Bl[wc * 48 + j * 16 + l16][kc + lk];
#pragma unroll
    for (int i = 0; i < 2; ++i)
#pragma unroll
      for (int j = 0; j < 3; ++j)
        acc[i][j] = __builtin_amdgcn_mfma_f32_16x16x32_bf16(
            af[i], bfr[j], acc[i][j], 0, 0, 0);
  }
#pragma unroll
  for (int i = 0; i < 2; ++i) {
#pragma unroll
    for (int j = 0; j < 3; ++j) {
#pragma unroll
      for (int v = 0; v < 4; ++v) {
        int m = m0 + wr * 32 + i * 16 + (lane >> 4) * 4 + v;
        int n = n0 + wc * 48 + j * 16 + l16;
        if (n < N) {
          float val = acc[i][j][v];
          val += bias ? bias[n] : 0.f;
          if (ACT == 1) val = 0.5f * val * (1.f + erff(val * 0.70710678118654752f));
          if (OUTBF16) ((unsigned short*)Cout)[(size_t)m * N + n] = f2bf(val);
          else         ((float*)Cout)[(size_t)m * N + n] = val;
        }
      }
    }
  }
}

// -------- bf16 MFMA GEMM --------------------------------------------------
#define BKP 40
template <int ACT, bool BIAS, bool RESID, bool OUT_BCS, bool GATEA, bool ABF16>
__global__ __launch_bounds__(256) void k_mfma(const void* __restrict__ Ap,
    const float* __restrict__ Bw, const float* __restrict__ bias,
    const float* __restrict__ resid, const unsigned short* __restrict__ XZg,
    float* __restrict__ Cmat, int M, int N, int K) {
  __shared__ unsigned short Al[64][BKP];
  __shared__ unsigned short Bl[96][BKP];
  int tid = threadIdx.x;
  int m0 = blockIdx.x * 64, n0 = blockIdx.y * 96;
  int wid = tid >> 6, lane = tid & 63;
  int wr = wid >> 1, wc = wid & 1;
  int l16 = lane & 15, lk = (lane >> 4) * 8;
  f32x4 acc[2][3];
#pragma unroll
  for (int i = 0; i < 2; ++i)
#pragma unroll
    for (int j = 0; j < 3; ++j) acc[i][j] = (f32x4){0.f, 0.f, 0.f, 0.f};

  for (int kk = 0; kk < K; kk += 32) {
    if (ABF16) {
      int row = tid >> 2, kq = tid & 3;
      int m = m0 + row;
      const unsigned short* As = (const unsigned short*)Ap;
      uint4 v = *(const uint4*)&As[(size_t)m * K + kk + kq * 8];
      if (GATEA) {
        unsigned short* pv = (unsigned short*)&v;
        int bb = m / S, ll = m - bb * S;
        int j = kk + kq * 8;
        int dir = j / DI; int e0 = j - dir * DI;
        int p = pos_from_l(dir, ll);
        uint4 zv = *(const uint4*)&XZg[((size_t)bb * S + p) * 384 + DI + e0];
        const unsigned short* zp = (const unsigned short*)&zv;
#pragma unroll
        for (int q = 0; q < 8; ++q)
          pv[q] = f2bf(bf2f(pv[q]) * silu(bf2f(zp[q])));
      }
      *(uint4*)&Al[row][kq * 8] = v;
    } else {
#pragma unroll
      for (int i = 0; i < 2; ++i) {
        int idx = tid + i * 256;
        int row = idx >> 3, kq = idx & 7;
        int m = m0 + row;
        const float* Af = (const float*)Ap;
        float4 v = *(const float4*)&Af[(size_t)m * K + kk + kq * 4];
        unsigned short* dst = &Al[row][kq * 4];
        dst[0] = f2bf(v.x); dst[1] = f2bf(v.y);
        dst[2] = f2bf(v.z); dst[3] = f2bf(v.w);
      }
    }
#pragma unroll
    for (int i = 0; i < 3; ++i) {
      int idx = tid + i * 256;
      int bn = idx >> 3, kq = idx & 7;
      int n = n0 + bn;
      float4 v = make_float4(0.f, 0.f, 0.f, 0.f);
      if (n < N) v = *(const float4*)&Bw[(size_t)n * K + kk + kq * 4];
      unsigned short* dst = &Bl[bn][kq * 4];
      dst[0] = f2bf(v.x); dst[1] = f2bf(v.y);
      dst[2] = f2bf(v.z); dst[3] = f2bf(v.w);
    }
    __syncthreads();
    bf16x8 af[2], bfr[3];
#pragma unroll
    for (int i = 0; i < 2; ++i)
      af[i] = *(const bf16x8*)&Al[wr * 32 + i * 16 + l16][lk];
#pragma unroll
    for (int j = 0; j < 3; ++j)
      bfr[j] = *(const bf16x8*)&Bl[wc * 48 + j * 16 + l16][lk];
#pragma unroll
    for (int i = 0; i < 2; ++i)
#pragma unroll
      for (int j = 0; j < 3; ++j)
        acc[i][j] = __builtin_amdgcn_mfma_f32_16x16x32_bf16(
            af[i], bfr[j], acc[i][j], 0, 0, 0);
    __syncthreads();
  }
#pragma unroll
  for (int i = 0; i < 2; ++i) {
#pragma unroll
    for (int j = 0; j < 3; ++j) {
#pragma unroll
      for (int v = 0; v < 4; ++v) {
        int m = m0 + wr * 32 + i * 16 + (lane >> 4) * 4 + v;
        int n = n0 + wc * 48 + j * 16 + l16;
        if (n < N) {
          float val = acc[i][j][v];
          if (BIAS) val += bias[n];
          if (ACT == 1) val = 0.5f * val * (1.f + erff(val * 0.70710678118654752f));
          if (RESID || OUT_BCS) {
            int bb = m / S, pp = m - bb * S;
            size_t oidx = ((size_t)bb * CC + n) * S + pp;
            if (RESID) val += resid[oidx];
            if (OUT_BCS) { Cmat[oidx] = val; continue; }
          }
          Cmat[(size_t)m * N + n] = val;
        }
      }
    }
  }
}

// ------- causal depthwise conv(4) + SiLU, bf16 in/out, 4 ch/thread -------
__global__ __launch_bounds__(256) void k_conv(const unsigned short* __restrict__ XZb,
    const float* __restrict__ cw, const float* __restrict__ cb,
    unsigned short* __restrict__ xcb) {
  int t = blockIdx.x * blockDim.x + threadIdx.x;
  if (t >= GG * S * 48) return;
  int q = t % 48; int gl = t / 48; int l = gl % S; int g = gl / S;
  int e0 = q * 4;
  int b = g / 3, dir = g - (g / 3) * 3;
  float cwv[4][4];
#pragma unroll
  for (int i = 0; i < 4; ++i)
    *(float4*)cwv[i] = *(const float4*)&cw[(e0 + i) * 4];
  float4 acc = *(const float4*)&cb[e0];
#pragma unroll
  for (int k = 0; k < 4; ++k) {
    int ls = l + k - 3;
    if (ls >= 0) {
      int p = pos_from_l(dir, ls);
      uint2 xz = *(const uint2*)&XZb[((size_t)b * S + p) * 384 + e0];
      const unsigned short* xp = (const unsigned short*)&xz;
      acc.x = fmaf(cwv[0][k], bf2f(xp[0]), acc.x);
      acc.y = fmaf(cwv[1][k], bf2f(xp[1]), acc.y);
      acc.z = fmaf(cwv[2][k], bf2f(xp[2]), acc.z);
      acc.w = fmaf(cwv[3][k], bf2f(xp[3]), acc.w);
    }
  }
  unsigned short o[4];
  o[0] = f2bf(acc.x * (1.f / (1.f + __expf(-acc.x))));
  o[1] = f2bf(acc.y * (1.f / (1.f + __expf(-acc.y))));
  o[2] = f2bf(acc.z * (1.f / (1.f + __expf(-acc.z))));
  o[3] = f2bf(acc.w * (1.f / (1.f + __expf(-acc.w))));
  *(uint2*)&xcb[(size_t)gl * DI + e0] = *(uint2*)o;
}

// ------- dt/r precompute (x4 per thread) -> packed (fp16 dt | fp16 r) ----
__global__ __launch_bounds__(256) void k_dtr(const float* __restrict__ xdbl,
    const float* __restrict__ Wdt, const float* __restrict__ bdt,
    const float* __restrict__ A_log, unsigned int* __restrict__ dr) {
  int t = blockIdx.x * blockDim.x + threadIdx.x;
  if (t >= GG * S * 48) return;
  int q = t % 48; int row = t / 48;
  int e0 = q * 4;
  const float* xr = xdbl + (size_t)row * ND;
  float r0 = xr[0], r1 = xr[1], r2 = xr[2], r3 = xr[3], r4 = xr[4], r5 = xr[5];
  unsigned int out[4];
#pragma unroll
  for (int i = 0; i < 4; ++i) {
    int e = e0 + i;
    const float* wp = &Wdt[e * RK];
    float a = bdt[e];
    a = fmaf(wp[0], r0, a); a = fmaf(wp[1], r1, a); a = fmaf(wp[2], r2, a);
    a = fmaf(wp[3], r3, a); a = fmaf(wp[4], r4, a); a = fmaf(wp[5], r5, a);
    float d = fmaxf(a, 0.f) + __logf(1.f + __expf(-fabsf(a)));
    float base = -__expf(A_log[e * NS]);
    out[i] = (unsigned int)f2h_bits(d) | ((unsigned int)f2h_bits(__expf(d * base)) << 16);
  }
  *(uint4*)&dr[(size_t)row * DI + e0] = *(uint4*)out;
}

// ======== scanA2: local recurrence + partial y + T, 16 states/thread =====
// Outputs: per-step T (fp16), per-step partial y (bf16), chunk-end EA (f32).
__global__ __launch_bounds__(192) void k_scanA2(const unsigned short* __restrict__ xcb,
    const unsigned int* __restrict__ dr, const float* __restrict__ xdbl,
    const float* __restrict__ A_log, const float* __restrict__ Dp,
    float* __restrict__ EA, unsigned short* __restrict__ Tb,
    unsigned short* __restrict__ ygb) {
  __shared__ float sBC[LC][32];
  int c = blockIdx.x, g = blockIdx.y;
  int tid = threadIdx.x;
  int e = tid;
  {
    const float* src = xdbl + ((size_t)g * S + c * LC) * ND + RK;
    for (int i = tid; i < LC * 32; i += 192) {
      int row = i >> 5, col = i & 31;
      sBC[row][col] = src[(size_t)row * ND + col];
    }
  }
  float base = -__expf(A_log[e * NS]);
  bool fast = true;
#pragma unroll
  for (int s = 1; s < NS; ++s) {
    float aes = -__expf(A_log[e * NS + s]);
    fast = fast && (fabsf(aes / base - (float)(s + 1)) < 1e-3f);
  }
  float dpe = Dp[e];
  f32x2 h2[8];
#pragma unroll
  for (int k = 0; k < 8; ++k) h2[k] = (f32x2){0.f, 0.f};
  float T = 0.f;
  size_t sbase = ((size_t)g * S + c * LC) * DI + e;
  const unsigned short* xp = xcb + sbase;
  const unsigned int* drp = dr + sbase;
  unsigned short* Tp = Tb + sbase;
  int b = g / 3, dir = g - (g / 3) * 3;
  unsigned short* yo = ygb + ((size_t)b * S + c * LC) * 576 + dir * DI + e;
  __syncthreads();
  if (fast) {
    unsigned short xb[2][8];
    unsigned int dv[2][8];
#pragma unroll
    for (int j = 0; j < 8; ++j) {
      xb[0][j] = xp[(size_t)j * DI];
      dv[0][j] = drp[(size_t)j * DI];
    }
#pragma unroll
    for (int blk = 0; blk < 5; ++blk) {
      int cb = blk & 1, nb = cb ^ 1;
      if (blk < 4) {
#pragma unroll
        for (int j = 0; j < 8; ++j) {
          xb[nb][j] = xp[(size_t)(blk * 8 + 8 + j) * DI];
          dv[nb][j] = drp[(size_t)(blk * 8 + 8 + j) * DI];
        }
      }
#pragma unroll
      for (int j = 0; j < 8; ++j) {
        int l = blk * 8 + j;
        float xv = bf2f(xb[cb][j]);
        unsigned int v = dv[cb][j];
        float d = h2f_bits((unsigned short)(v & 0xffff));
        float r = h2f_bits((unsigned short)(v >> 16));
        T += d;
        Tp[(size_t)l * DI] = f2h_bits(T);
        float w = d * xv;
        float r2 = r * r, r4 = r2 * r2, r8 = r4 * r4;
        f32x2 r2v = {r2, r2}, r4v = {r4, r4}, r8v = {r8, r8};
        f32x2 m0 = {r, r2};
        f32x2 m1 = m0 * r2v, m2 = m0 * r4v, m3 = m1 * r4v;
        f32x2 m4 = m0 * r8v, m5 = m1 * r8v, m6 = m2 * r8v, m7 = m3 * r8v;
        f32x2 wv = {w, w};
        float4 Ba = *(const float4*)&sBC[l][0];
        float4 Bb = *(const float4*)&sBC[l][4];
        float4 Bc = *(const float4*)&sBC[l][8];
        float4 Bd = *(const float4*)&sBC[l][12];
        float4 Ca = *(const float4*)&sBC[l][16];
        float4 Cb2 = *(const float4*)&sBC[l][20];
        float4 Cc = *(const float4*)&sBC[l][24];
        float4 Cd = *(const float4*)&sBC[l][28];
        f32x2 ya = {xv * dpe, 0.f};
        h2[0] = m0 * h2[0] + wv * (f32x2){Ba.x, Ba.y}; ya += h2[0] * (f32x2){Ca.x, Ca.y};
        h2[1] = m1 * h2[1] + wv * (f32x2){Ba.z, Ba.w}; ya += h2[1] * (f32x2){Ca.z, Ca.w};
        h2[2] = m2 * h2[2] + wv * (f32x2){Bb.x, Bb.y}; ya += h2[2] * (f32x2){Cb2.x, Cb2.y};
        h2[3] = m3 * h2[3] + wv * (f32x2){Bb.z, Bb.w}; ya += h2[3] * (f32x2){Cb2.z, Cb2.w};
        h2[4] = m4 * h2[4] + wv * (f32x2){Bc.x, Bc.y}; ya += h2[4] * (f32x2){Cc.x, Cc.y};
        h2[5] = m5 * h2[5] + wv * (f32x2){Bc.z, Bc.w}; ya += h2[5] * (f32x2){Cc.z, Cc.w};
        h2[6] = m6 * h2[6] + wv * (f32x2){Bd.x, Bd.y}; ya += h2[6] * (f32x2){Cd.x, Cd.y};
        h2[7] = m7 * h2[7] + wv * (f32x2){Bd.z, Bd.w}; ya += h2[7] * (f32x2){Cd.z, Cd.w};
        yo[(size_t)l * 576] = f2bf(ya[0] + ya[1]);
      }
    }
  } else {
    float Aes[NS];
#pragma unroll
    for (int s = 0; s < NS; ++s) Aes[s] = -__expf(A_log[e * NS + s]);
#pragma unroll 1
    for (int l = 0; l < LC; ++l) {
      unsigned int v = drp[(size_t)l * DI];
      float d = h2f_bits((unsigned short)(v & 0xffff));
      float xv = bf2f(xp[(size_t)l * DI]);
      T += d;
      Tp[(size_t)l * DI] = f2h_bits(T);
      float w = d * xv;
      float y = xv * dpe;
#pragma unroll
      for (int s = 0; s < NS; ++s) {
        float q = __expf(d * Aes[s]);
        float hk = fmaf(q, h2[s >> 1][s & 1], w * sBC[l][s]);
        h2[s >> 1][s & 1] = hk;
        y = fmaf(hk, sBC[l][16 + s], y);
      }
      yo[(size_t)l * 576] = f2bf(y);
    }
  }
  float* ep = EA + (((size_t)g * NC + c) * DI + e) * NS;
#pragma unroll
  for (int s = 0; s < NS; s += 4)
    *(float4*)&ep[s] = make_float4(h2[s>>1][0], h2[s>>1][1], h2[(s>>1)+1][0], h2[(s>>1)+1][1]);
}

// inter-chunk combine; q computed from chunk-end T (PA eliminated).
// Hin aliases EA (group loads precede group stores).
__global__ __launch_bounds__(256) void k_scanB(const unsigned short* __restrict__ Tb,
    const float* __restrict__ A_log, const float* EA, float* Hin) {
  int idx = blockIdx.x * blockDim.x + threadIdx.x;
  if (idx >= GG * DI * NS) return;
  int g = idx / (DI * NS); int rem = idx - g * (DI * NS);
  int e = rem >> 4, s = rem & 15;
  float Aes = -__expf(A_log[e * NS + s]);
  size_t stride = (size_t)DI * NS;
  size_t b0 = (size_t)g * NC * stride + rem;
  // T_end of chunk c: Tb[(g*S + c*LC + LC-1)*DI + e]
  const unsigned short* Tpe = Tb + ((size_t)g * S + (LC - 1)) * DI + e;
  float h = 0.f;
  for (int c0 = 0; c0 < NC; c0 += 8) {
    float t8[8], e8[8];
#pragma unroll
    for (int j = 0; j < 8; ++j) {
      t8[j] = h2f_bits(Tpe[(size_t)(c0 + j) * LC * DI]);
      e8[j] = EA[b0 + (size_t)(c0 + j) * stride];
    }
    float q8[8];
#pragma unroll
    for (int j = 0; j < 8; ++j) q8[j] = __expf(Aes * t8[j]);
#pragma unroll
    for (int j = 0; j < 8; ++j) {
      size_t ix = b0 + (size_t)(c0 + j) * stride;
      Hin[ix] = h;
      h = fmaf(q8[j], h, e8[j]);
    }
  }
}

// ======== scanC2: correction pass y += C * R^(s+1) * h_in ================
__global__ __launch_bounds__(192) void k_scanC2(const unsigned short* __restrict__ Tb,
    const float* __restrict__ xdbl, const float* __restrict__ A_log,
    const float* __restrict__ Hin, unsigned short* __restrict__ ygb) {
  __shared__ float sC[LC][16];
  int c = blockIdx.x, g = blockIdx.y;
  int tid = threadIdx.x;
  int e = tid;
  {
    const float* src = xdbl + ((size_t)g * S + c * LC) * ND + RK + 16;
    for (int i = tid; i < LC * 16; i += 192) {
      int row = i >> 4, col = i & 15;
      sC[row][col] = src[(size_t)row * ND + col];
    }
  }
  float base = -__expf(A_log[e * NS]);
  bool fast = true;
#pragma unroll
  for (int s = 1; s < NS; ++s) {
    float aes = -__expf(A_log[e * NS + s]);
    fast = fast && (fabsf(aes / base - (float)(s + 1)) < 1e-3f);
  }
  const float* hp = Hin + (((size_t)g * NC + c) * DI + e) * NS;
  float4 hv0 = *(const float4*)(hp + 0);
  float4 hv1 = *(const float4*)(hp + 4);
  float4 hv2 = *(const float4*)(hp + 8);
  float4 hv3 = *(const float4*)(hp + 12);
  f32x2 hin[8] = {{hv0.x, hv0.y}, {hv0.z, hv0.w}, {hv1.x, hv1.y}, {hv1.z, hv1.w},
                  {hv2.x, hv2.y}, {hv2.z, hv2.w}, {hv3.x, hv3.y}, {hv3.z, hv3.w}};
  float hmag = fabsf(hv0.x) + fabsf(hv0.y) + fabsf(hv0.z) + fabsf(hv0.w) +
               fabsf(hv1.x) + fabsf(hv1.y) + fabsf(hv1.z) + fabsf(hv1.w) +
               fabsf(hv2.x) + fabsf(hv2.y) + fabsf(hv2.z) + fabsf(hv2.w) +
               fabsf(hv3.x) + fabsf(hv3.y) + fabsf(hv3.z) + fabsf(hv3.w);
  size_t sbase = ((size_t)g * S + c * LC) * DI + e;
  const unsigned short* Tp = Tb + sbase;
  int b = g / 3, dir = g - (g / 3) * 3;
  unsigned short* yo = ygb + ((size_t)b * S + c * LC) * 576 + dir * DI + e;
  __syncthreads();
  if (__builtin_amdgcn_ballot_w64(hmag != 0.f) == 0ull) return;
  if (fast) {
    unsigned short tb2[2][8], yb[2][8];
#pragma unroll
    for (int j = 0; j < 8; ++j) {
      tb2[0][j] = Tp[(size_t)j * DI];
      yb[0][j] = yo[(size_t)j * 576];
    }
#pragma unroll
    for (int blk = 0; blk < 5; ++blk) {
      int cb = blk & 1, nb = cb ^ 1;
      if (blk < 4) {
#pragma unroll
        for (int j = 0; j < 8; ++j) {
          tb2[nb][j] = Tp[(size_t)(blk * 8 + 8 + j) * DI];
          yb[nb][j] = yo[(size_t)(blk * 8 + 8 + j) * 576];
        }
      }
#pragma unroll
      for (int j = 0; j < 8; ++j) {
        int l = blk * 8 + j;
        float T = h2f_bits(tb2[cb][j]);
        float R = __expf(base * T);
        float R2 = R * R, R4 = R2 * R2, R8 = R4 * R4;
        f32x2 R2v = {R2, R2}, R4v = {R4, R4}, R8v = {R8, R8};
        f32x2 q0 = {R, R2};
        f32x2 q1 = q0 * R2v, q2 = q0 * R4v, q3 = q1 * R4v;
        f32x2 q4 = q0 * R8v, q5 = q1 * R8v, q6 = q2 * R8v, q7 = q3 * R8v;
        float4 Ca = *(const float4*)&sC[l][0];
        float4 Cb2 = *(const float4*)&sC[l][4];
        float4 Cc = *(const float4*)&sC[l][8];
        float4 Cd = *(const float4*)&sC[l][12];
        f32x2 ca = (hin[0] * q0) * (f32x2){Ca.x, Ca.y};
        ca += (hin[1] * q1) * (f32x2){Ca.z, Ca.w};
        ca += (hin[2] * q2) * (f32x2){Cb2.x, Cb2.y};
        ca += (hin[3] * q3) * (f32x2){Cb2.z, Cb2.w};
        ca += (hin[4] * q4) * (f32x2){Cc.x, Cc.y};
        ca += (hin[5] * q5) * (f32x2){Cc.z, Cc.w};
        ca += (hin[6] * q6) * (f32x2){Cd.x, Cd.y};
        ca += (hin[7] * q7) * (f32x2){Cd.z, Cd.w};
        float y = bf2f(yb[cb][j]) + ca[0] + ca[1];
        yo[(size_t)l * 576] = f2bf(y);
      }
    }
  } else {
    float Aes[NS];
#pragma unroll
    for (int s = 0; s < NS; ++s) Aes[s] = -__expf(A_log[e * NS + s]);
#pragma unroll 1
    for (int l = 0; l < LC; ++l) {
      float T = h2f_bits(Tp[(size_t)l * DI]);
      float y = bf2f(yo[(size_t)l * 576]);
#pragma unroll
      for (int s = 0; s < NS; ++s) {
        float W = __expf(Aes[s] * T);
        y = fmaf(hin[s >> 1][s & 1] * W, sC[l][s], y);
      }
      yo[(size_t)l * 576] = f2bf(y);
    }
  }
}

// ---------------- fold Wout into proj_w: Mcat[o, dir*192+e] --------------
__global__ __launch_bounds__(256) void k_foldW(const float* __restrict__ proj_w,
    const float* __restrict__ Wout, float* __restrict__ Mcat) {
  int t = blockIdx.x * blockDim.x + threadIdx.x;
  if (t >= CC * 576) return;
  int o = t / 576; int j = t - o * 576; int dir = j / DI; int e = j - dir * DI;
  float a = 0.f;
  for (int c2 = 0; c2 < CC; ++c2)
    a = fmaf(proj_w[o * 288 + dir * CC + c2], Wout[c2 * DI + e], a);
  Mcat[t] = a;
}

extern "C" void kernel_launch(void* const* d_in, const int* in_sizes, int n_in,
                              void* d_out, int out_size, void* d_ws, size_t ws_size,
                              hipStream_t stream) {
  const float* x      = (const float*)d_in[0];
  const float* ln_w   = (const float*)d_in[1];
  const float* ln_b   = (const float*)d_in[2];
  const float* mln_w  = (const float*)d_in[3];
  const float* mln_b  = (const float*)d_in[4];
  const float* Win    = (const float*)d_in[5];
  const float* conv_w = (const float*)d_in[6];
  const float* conv_b = (const float*)d_in[7];
  const float* Wx     = (const float*)d_in[8];
  const float* Wdt    = (const float*)d_in[9];
  const float* bdt    = (const float*)d_in[10];
  const float* A_log  = (const float*)d_in[11];
  const float* Dp     = (const float*)d_in[12];
  const float* Wout   = (const float*)d_in[13];
  const float* proj_w = (const float*)d_in[14];
  const float* proj_b = (const float*)d_in[15];
  const float* fc1_w  = (const float*)d_in[16];
  const float* fc1_b  = (const float*)d_in[17];
  const float* fc2_w  = (const float*)d_in[18];
  const float* fc2_b  = (const float*)d_in[19];

  float* ws = (float*)d_ws;
  size_t off = 0;
  float* ores = ws + off; off += (size_t)BB * S * CC;        // f32
  float* XZf  = ws + off; off += (size_t)BB * S * 384 / 2;   // bf16 (+h1 alias)
  float* xcf  = ws + off; off += (size_t)GG * S * DI / 2;    // bf16
  float* xdbl = ws + off; off += (size_t)GG * S * ND;        // f32
  float* drf  = ws + off; off += (size_t)GG * S * DI;        // packed u32
  float* Tf   = ws + off; off += (size_t)GG * S * DI / 2;    // fp16
  float* EA   = ws + off; off += (size_t)GG * NC * DI * NS;  // 3.686M fl
  float* yg   = ws + off; off += (size_t)BB * S * 576 / 2;   // bf16
  float* Mcat = ws + off; off += (size_t)CC * 576;
  if (ws_size < off * sizeof(float)) return;                 // ~125 MB; guard
  float* Hin  = EA;    // in-place combine (group loads precede stores)
  unsigned short* XZb = (unsigned short*)XZf;
  unsigned short* xcb = (unsigned short*)xcf;
  unsigned int*   dr  = (unsigned int*)drf;
  unsigned short* Tb  = (unsigned short*)Tf;
  unsigned short* ygb = (unsigned short*)yg;
  unsigned short* h1  = (unsigned short*)XZf;

  k_lnmfma<0, true, true><<<dim3(BB * S / 64, 4), 256, 0, stream>>>(
      x, ln_w, ln_b, mln_w, mln_b, Win, nullptr, XZb, BB * S, 384);
  k_conv<<<(GG * S * 48 + 255) / 256, 256, 0, stream>>>(XZb, conv_w, conv_b, xcb);
  k_mfma<0, false, false, false, false, true>
      <<<dim3(GG * S / 64, 1), 256, 0, stream>>>(
      xcb, Wx, nullptr, nullptr, nullptr, xdbl, GG * S, ND, DI);
  k_dtr<<<(GG * S * 48 + 255) / 256, 256, 0, stream>>>(
      xdbl, Wdt, bdt, A_log, dr);
  k_scanA2<<<dim3(NC, GG), 192, 0, stream>>>(
      xcb, dr, xdbl, A_log, Dp, EA, Tb, ygb);
  k_scanB<<<(GG * DI * NS + 255) / 256, 256, 0, stream>>>(Tb, A_log, EA, Hin);
  k_scanC2<<<dim3(NC, GG), 192, 0, stream>>>(
      Tb, xdbl, A_log, Hin, ygb);
  k_foldW<<<(CC * 576 + 255) / 256, 256, 0, stream>>>(proj_w, Wout, Mcat);
  k_mfma<0, true, true, true, true, true>
      <<<dim3(BB * S / 64, 1), 256, 0, stream>>>(
      ygb, Mcat, proj_b, x, XZb, ores, BB * S, CC, 576);
  k_lnmfma<1, false, true><<<dim3(BB * S / 64, 4), 256, 0, stream>>>(
      ores, ln_w, ln_b, nullptr, nullptr, fc1_w, fc1_b, h1, BB * S, 384);
  k_mfma<0, true, true, true, false, true>
      <<<dim3(BB * S / 64, 1), 256, 0, stream>>>(
      h1, fc2_w, fc2_b, ores, nullptr, (float*)d_out, BB * S, CC, 384);
}

// Round 18
// 232.231 us; speedup vs baseline: 1.2469x; 1.1033x over previous
//
#include <hip/hip_runtime.h>
#include <hip/hip_fp16.h>
#include <math.h>

// Problem constants (fixed by reference)
#define S   8000     // L = 20*20*20
#define BB  2
#define CC  96
#define DI  192      // d_inner
#define NS  16       // d_state
#define RK  6        // dt_rank
#define GG  6        // B * 3 directions
#define NC  200      // scan chunks
#define LC  40       // chunk length
#define ND  38       // dt_rank + 2*d_state

typedef __attribute__((ext_vector_type(8))) short bf16x8;
typedef __attribute__((ext_vector_type(4))) float f32x4;
typedef __attribute__((ext_vector_type(2))) float f32x2;

__device__ __forceinline__ int pos_from_l(int dir, int l) {
  if (dir == 0) return l;
  int a  = l / 400;
  int r  = l - a * 400;
  int bq = r / 20;
  int cq = r - bq * 20;
  if (dir == 1) return cq * 400 + a * 20 + bq;
  return bq * 400 + cq * 20 + a;
}

__device__ __forceinline__ float silu(float z) {
  return z / (1.f + __expf(-z));
}
__device__ __forceinline__ unsigned short f2bf(float x) {
  unsigned int u = __float_as_uint(x);
  u += 0x7FFFu + ((u >> 16) & 1u);
  return (unsigned short)(u >> 16);
}
__device__ __forceinline__ float bf2f(unsigned short h) {
  return __uint_as_float((unsigned int)h << 16);
}
__device__ __forceinline__ float h2f_bits(unsigned short h) {
  __half hh = *reinterpret_cast<__half*>(&h);
  return __half2float(hh);
}
__device__ __forceinline__ unsigned short f2h_bits(float x) {
  __half hh = __float2half(x);
  return *reinterpret_cast<unsigned short*>(&hh);
}
__device__ __forceinline__ float quad_sum(float x) {
  x += __int_as_float(__builtin_amdgcn_update_dpp(0, __float_as_int(x), 0xB1, 0xF, 0xF, true));
  x += __int_as_float(__builtin_amdgcn_update_dpp(0, __float_as_int(x), 0x4E, 0xF, 0xF, true));
  return x;
}

// ======== fused LayerNorm + bf16 MFMA GEMM over K=CC=96 ==================
template <int ACT, bool DOUBLE, bool OUTBF16>
__global__ __launch_bounds__(256) void k_lnmfma(const float* __restrict__ Xsrc,
    const float* __restrict__ lnw, const float* __restrict__ lnb,
    const float* __restrict__ mlnw, const float* __restrict__ mlnb,
    const float* __restrict__ Bw, const float* __restrict__ bias,
    void* __restrict__ Cout, int M, int N) {
  __shared__ float Xf[64][97];
  __shared__ unsigned short Al[64][104];
  __shared__ unsigned short Bl[96][104];
  int tid = threadIdx.x;
  int m0 = blockIdx.x * 64, n0 = blockIdx.y * 96;
  int b = m0 / S, pos0 = m0 - b * S;
  for (int idx = tid; idx < 64 * 96; idx += 256) {
    int row = idx & 63, c = idx >> 6;
    Xf[row][c] = Xsrc[((size_t)b * CC + c) * S + pos0 + row];
  }
  for (int idx = tid; idx < 96 * 24; idx += 256) {
    int bn = idx / 24, kq = idx - bn * 24;
    int n = n0 + bn;
    float4 v = make_float4(0.f, 0.f, 0.f, 0.f);
    if (n < N) v = *(const float4*)&Bw[(size_t)n * 96 + kq * 4];
    unsigned short* dst = &Bl[bn][kq * 4];
    dst[0] = f2bf(v.x); dst[1] = f2bf(v.y);
    dst[2] = f2bf(v.z); dst[3] = f2bf(v.w);
  }
  __syncthreads();
  {
    int row = tid >> 2, part = tid & 3;
    const float* xr = &Xf[row][part * 24];
    float s1 = 0.f, s2 = 0.f;
#pragma unroll
    for (int i = 0; i < 24; ++i) { float v = xr[i]; s1 += v; s2 += v * v; }
    s1 = quad_sum(s1); s2 = quad_sum(s2);
    float u = s1 * (1.f / 96.f);
    float var = s2 * (1.f / 96.f) - u * u;
    float rstd = rsqrtf(var + 1e-6f);
    if (DOUBLE) {
      float t1 = 0.f, t2 = 0.f;
#pragma unroll
      for (int i = 0; i < 24; ++i) {
        int c = part * 24 + i;
        float y1 = fmaf(lnw[c], (xr[i] - u) * rstd, lnb[c]);
        t1 += y1; t2 += y1 * y1;
      }
      t1 = quad_sum(t1); t2 = quad_sum(t2);
      float u2 = t1 * (1.f / 96.f);
      float var2 = t2 * (1.f / 96.f) - u2 * u2;
      float rstd2 = rsqrtf(var2 + 1e-5f);
#pragma unroll
      for (int i = 0; i < 24; ++i) {
        int c = part * 24 + i;
        float y1 = fmaf(lnw[c], (xr[i] - u) * rstd, lnb[c]);
        Al[row][c] = f2bf(fmaf(mlnw[c], (y1 - u2) * rstd2, mlnb[c]));
      }
    } else {
#pragma unroll
      for (int i = 0; i < 24; ++i) {
        int c = part * 24 + i;
        Al[row][c] = f2bf(fmaf(lnw[c], (xr[i] - u) * rstd, lnb[c]));
      }
    }
  }
  __syncthreads();
  int wid = tid >> 6, lane = tid & 63;
  int wr = wid >> 1, wc = wid & 1;
  int l16 = lane & 15, lk = (lane >> 4) * 8;
  f32x4 acc[2][3];
#pragma unroll
  for (int i = 0; i < 2; ++i)
#pragma unroll
    for (int j = 0; j < 3; ++j) acc[i][j] = (f32x4){0.f, 0.f, 0.f, 0.f};
#pragma unroll
  for (int kc = 0; kc < 96; kc += 32) {
    bf16x8 af[2], bfr[3];
#pragma unroll
    for (int i = 0; i < 2; ++i)
      af[i] = *(const bf16x8*)&Al[wr * 32 + i * 16 + l16][kc + lk];
#pragma unroll
    for (int j = 0; j < 3; ++j)
      bfr[j] = *(const bf16x8*)&Bl[wc * 48 + j * 16 + l16][kc + lk];
#pragma unroll
    for (int i = 0; i < 2; ++i)
#pragma unroll
      for (int j = 0; j < 3; ++j)
        acc[i][j] = __builtin_amdgcn_mfma_f32_16x16x32_bf16(
            af[i], bfr[j], acc[i][j], 0, 0, 0);
  }
#pragma unroll
  for (int i = 0; i < 2; ++i) {
#pragma unroll
    for (int j = 0; j < 3; ++j) {
#pragma unroll
      for (int v = 0; v < 4; ++v) {
        int m = m0 + wr * 32 + i * 16 + (lane >> 4) * 4 + v;
        int n = n0 + wc * 48 + j * 16 + l16;
        if (n < N) {
          float val = acc[i][j][v];
          val += bias ? bias[n] : 0.f;
          if (ACT == 1) val = 0.5f * val * (1.f + erff(val * 0.70710678118654752f));
          if (OUTBF16) ((unsigned short*)Cout)[(size_t)m * N + n] = f2bf(val);
          else         ((float*)Cout)[(size_t)m * N + n] = val;
        }
      }
    }
  }
}

// -------- bf16 MFMA GEMM --------------------------------------------------
#define BKP 40
template <int ACT, bool BIAS, bool RESID, bool OUT_BCS, bool GATEA, bool ABF16>
__global__ __launch_bounds__(256) void k_mfma(const void* __restrict__ Ap,
    const float* __restrict__ Bw, const float* __restrict__ bias,
    const float* __restrict__ resid, const unsigned short* __restrict__ XZg,
    float* __restrict__ Cmat, int M, int N, int K) {
  __shared__ unsigned short Al[64][BKP];
  __shared__ unsigned short Bl[96][BKP];
  int tid = threadIdx.x;
  int m0 = blockIdx.x * 64, n0 = blockIdx.y * 96;
  int wid = tid >> 6, lane = tid & 63;
  int wr = wid >> 1, wc = wid & 1;
  int l16 = lane & 15, lk = (lane >> 4) * 8;
  f32x4 acc[2][3];
#pragma unroll
  for (int i = 0; i < 2; ++i)
#pragma unroll
    for (int j = 0; j < 3; ++j) acc[i][j] = (f32x4){0.f, 0.f, 0.f, 0.f};

  for (int kk = 0; kk < K; kk += 32) {
    if (ABF16) {
      int row = tid >> 2, kq = tid & 3;
      int m = m0 + row;
      const unsigned short* As = (const unsigned short*)Ap;
      uint4 v = *(const uint4*)&As[(size_t)m * K + kk + kq * 8];
      if (GATEA) {
        unsigned short* pv = (unsigned short*)&v;
        int bb = m / S, ll = m - bb * S;
        int j = kk + kq * 8;
        int dir = j / DI; int e0 = j - dir * DI;
        int p = pos_from_l(dir, ll);
        uint4 zv = *(const uint4*)&XZg[((size_t)bb * S + p) * 384 + DI + e0];
        const unsigned short* zp = (const unsigned short*)&zv;
#pragma unroll
        for (int q = 0; q < 8; ++q)
          pv[q] = f2bf(bf2f(pv[q]) * silu(bf2f(zp[q])));
      }
      *(uint4*)&Al[row][kq * 8] = v;
    } else {
#pragma unroll
      for (int i = 0; i < 2; ++i) {
        int idx = tid + i * 256;
        int row = idx >> 3, kq = idx & 7;
        int m = m0 + row;
        const float* Af = (const float*)Ap;
        float4 v = *(const float4*)&Af[(size_t)m * K + kk + kq * 4];
        unsigned short* dst = &Al[row][kq * 4];
        dst[0] = f2bf(v.x); dst[1] = f2bf(v.y);
        dst[2] = f2bf(v.z); dst[3] = f2bf(v.w);
      }
    }
#pragma unroll
    for (int i = 0; i < 3; ++i) {
      int idx = tid + i * 256;
      int bn = idx >> 3, kq = idx & 7;
      int n = n0 + bn;
      float4 v = make_float4(0.f, 0.f, 0.f, 0.f);
      if (n < N) v = *(const float4*)&Bw[(size_t)n * K + kk + kq * 4];
      unsigned short* dst = &Bl[bn][kq * 4];
      dst[0] = f2bf(v.x); dst[1] = f2bf(v.y);
      dst[2] = f2bf(v.z); dst[3] = f2bf(v.w);
    }
    __syncthreads();
    bf16x8 af[2], bfr[3];
#pragma unroll
    for (int i = 0; i < 2; ++i)
      af[i] = *(const bf16x8*)&Al[wr * 32 + i * 16 + l16][lk];
#pragma unroll
    for (int j = 0; j < 3; ++j)
      bfr[j] = *(const bf16x8*)&Bl[wc * 48 + j * 16 + l16][lk];
#pragma unroll
    for (int i = 0; i < 2; ++i)
#pragma unroll
      for (int j = 0; j < 3; ++j)
        acc[i][j] = __builtin_amdgcn_mfma_f32_16x16x32_bf16(
            af[i], bfr[j], acc[i][j], 0, 0, 0);
    __syncthreads();
  }
#pragma unroll
  for (int i = 0; i < 2; ++i) {
#pragma unroll
    for (int j = 0; j < 3; ++j) {
#pragma unroll
      for (int v = 0; v < 4; ++v) {
        int m = m0 + wr * 32 + i * 16 + (lane >> 4) * 4 + v;
        int n = n0 + wc * 48 + j * 16 + l16;
        if (n < N) {
          float val = acc[i][j][v];
          if (BIAS) val += bias[n];
          if (ACT == 1) val = 0.5f * val * (1.f + erff(val * 0.70710678118654752f));
          if (RESID || OUT_BCS) {
            int bb = m / S, pp = m - bb * S;
            size_t oidx = ((size_t)bb * CC + n) * S + pp;
            if (RESID) val += resid[oidx];
            if (OUT_BCS) { Cmat[oidx] = val; continue; }
          }
          Cmat[(size_t)m * N + n] = val;
        }
      }
    }
  }
}

// ------- causal depthwise conv(4) + SiLU, bf16 in/out, 4 ch/thread -------
__global__ __launch_bounds__(256) void k_conv(const unsigned short* __restrict__ XZb,
    const float* __restrict__ cw, const float* __restrict__ cb,
    unsigned short* __restrict__ xcb) {
  int t = blockIdx.x * blockDim.x + threadIdx.x;
  if (t >= GG * S * 48) return;
  int q = t % 48; int gl = t / 48; int l = gl % S; int g = gl / S;
  int e0 = q * 4;
  int b = g / 3, dir = g - (g / 3) * 3;
  float cwv[4][4];
#pragma unroll
  for (int i = 0; i < 4; ++i)
    *(float4*)cwv[i] = *(const float4*)&cw[(e0 + i) * 4];
  float4 acc = *(const float4*)&cb[e0];
#pragma unroll
  for (int k = 0; k < 4; ++k) {
    int ls = l + k - 3;
    if (ls >= 0) {
      int p = pos_from_l(dir, ls);
      uint2 xz = *(const uint2*)&XZb[((size_t)b * S + p) * 384 + e0];
      const unsigned short* xp = (const unsigned short*)&xz;
      acc.x = fmaf(cwv[0][k], bf2f(xp[0]), acc.x);
      acc.y = fmaf(cwv[1][k], bf2f(xp[1]), acc.y);
      acc.z = fmaf(cwv[2][k], bf2f(xp[2]), acc.z);
      acc.w = fmaf(cwv[3][k], bf2f(xp[3]), acc.w);
    }
  }
  unsigned short o[4];
  o[0] = f2bf(acc.x * (1.f / (1.f + __expf(-acc.x))));
  o[1] = f2bf(acc.y * (1.f / (1.f + __expf(-acc.y))));
  o[2] = f2bf(acc.z * (1.f / (1.f + __expf(-acc.z))));
  o[3] = f2bf(acc.w * (1.f / (1.f + __expf(-acc.w))));
  *(uint2*)&xcb[(size_t)gl * DI + e0] = *(uint2*)o;
}

// ======== scanA2: dt/r in-kernel + local recurrence + partial y + T ======
// sBC[l]: cols 0..5 dt_r, 8..23 B, 24..39 C. Outputs: T (fp16/step),
// partial y (bf16/step), chunk-end EA (f32).
__global__ __launch_bounds__(192) void k_scanA2(const unsigned short* __restrict__ xcb,
    const float* __restrict__ xdbl, const float* __restrict__ Wdt,
    const float* __restrict__ bdt, const float* __restrict__ A_log,
    const float* __restrict__ Dp, float* __restrict__ EA,
    unsigned short* __restrict__ Tb, unsigned short* __restrict__ ygb) {
  __shared__ float sBC[LC][40];
  int c = blockIdx.x, g = blockIdx.y;
  int tid = threadIdx.x;
  int e = tid;
  {
    const float* src = xdbl + ((size_t)g * S + c * LC) * ND;
    for (int i = tid; i < LC * ND; i += 192) {
      int row = i / ND, col = i - row * ND;
      int dst = (col < RK) ? col : col + 2;
      sBC[row][dst] = src[(size_t)row * ND + col];
    }
  }
  float wdt[RK];
#pragma unroll
  for (int r = 0; r < RK; ++r) wdt[r] = Wdt[e * RK + r];
  float bde = bdt[e];
  float base = -__expf(A_log[e * NS]);
  bool fast = true;
#pragma unroll
  for (int s = 1; s < NS; ++s) {
    float aes = -__expf(A_log[e * NS + s]);
    fast = fast && (fabsf(aes / base - (float)(s + 1)) < 1e-3f);
  }
  float dpe = Dp[e];
  f32x2 h2[8];
#pragma unroll
  for (int k = 0; k < 8; ++k) h2[k] = (f32x2){0.f, 0.f};
  float T = 0.f;
  size_t sbase = ((size_t)g * S + c * LC) * DI + e;
  const unsigned short* xp = xcb + sbase;
  unsigned short* Tp = Tb + sbase;
  int b = g / 3, dir = g - (g / 3) * 3;
  unsigned short* yo = ygb + ((size_t)b * S + c * LC) * 576 + dir * DI + e;
  __syncthreads();
  if (fast) {
    unsigned short xb[2][8];
#pragma unroll
    for (int j = 0; j < 8; ++j) xb[0][j] = xp[(size_t)j * DI];
#pragma unroll
    for (int blk = 0; blk < 5; ++blk) {
      int cb = blk & 1, nb = cb ^ 1;
      if (blk < 4) {
#pragma unroll
        for (int j = 0; j < 8; ++j)
          xb[nb][j] = xp[(size_t)(blk * 8 + 8 + j) * DI];
      }
#pragma unroll
      for (int j = 0; j < 8; ++j) {
        int l = blk * 8 + j;
        float xv = bf2f(xb[cb][j]);
        float a = bde;
        {
          float4 q0 = *(const float4*)&sBC[l][0];
          float2 q1 = *(const float2*)&sBC[l][4];
          a = fmaf(wdt[0], q0.x, a); a = fmaf(wdt[1], q0.y, a);
          a = fmaf(wdt[2], q0.z, a); a = fmaf(wdt[3], q0.w, a);
          a = fmaf(wdt[4], q1.x, a); a = fmaf(wdt[5], q1.y, a);
        }
        float d = fmaxf(a, 0.f) + __logf(1.f + __expf(-fabsf(a)));
        float r = __expf(d * base);
        T += d;
        Tp[(size_t)l * DI] = f2h_bits(T);
        float w = d * xv;
        float r2 = r * r, r4 = r2 * r2, r8 = r4 * r4;
        f32x2 r2v = {r2, r2}, r4v = {r4, r4}, r8v = {r8, r8};
        f32x2 m0 = {r, r2};
        f32x2 m1 = m0 * r2v, m2 = m0 * r4v, m3 = m1 * r4v;
        f32x2 m4 = m0 * r8v, m5 = m1 * r8v, m6 = m2 * r8v, m7 = m3 * r8v;
        f32x2 wv = {w, w};
        float4 Ba = *(const float4*)&sBC[l][8];
        float4 Bb = *(const float4*)&sBC[l][12];
        float4 Bc = *(const float4*)&sBC[l][16];
        float4 Bd = *(const float4*)&sBC[l][20];
        float4 Ca = *(const float4*)&sBC[l][24];
        float4 Cb2 = *(const float4*)&sBC[l][28];
        float4 Cc = *(const float4*)&sBC[l][32];
        float4 Cd = *(const float4*)&sBC[l][36];
        f32x2 ya = {xv * dpe, 0.f};
        h2[0] = m0 * h2[0] + wv * (f32x2){Ba.x, Ba.y}; ya += h2[0] * (f32x2){Ca.x, Ca.y};
        h2[1] = m1 * h2[1] + wv * (f32x2){Ba.z, Ba.w}; ya += h2[1] * (f32x2){Ca.z, Ca.w};
        h2[2] = m2 * h2[2] + wv * (f32x2){Bb.x, Bb.y}; ya += h2[2] * (f32x2){Cb2.x, Cb2.y};
        h2[3] = m3 * h2[3] + wv * (f32x2){Bb.z, Bb.w}; ya += h2[3] * (f32x2){Cb2.z, Cb2.w};
        h2[4] = m4 * h2[4] + wv * (f32x2){Bc.x, Bc.y}; ya += h2[4] * (f32x2){Cc.x, Cc.y};
        h2[5] = m5 * h2[5] + wv * (f32x2){Bc.z, Bc.w}; ya += h2[5] * (f32x2){Cc.z, Cc.w};
        h2[6] = m6 * h2[6] + wv * (f32x2){Bd.x, Bd.y}; ya += h2[6] * (f32x2){Cd.x, Cd.y};
        h2[7] = m7 * h2[7] + wv * (f32x2){Bd.z, Bd.w}; ya += h2[7] * (f32x2){Cd.z, Cd.w};
        yo[(size_t)l * 576] = f2bf(ya[0] + ya[1]);
      }
    }
  } else {
    float Aes[NS];
#pragma unroll
    for (int s = 0; s < NS; ++s) Aes[s] = -__expf(A_log[e * NS + s]);
#pragma unroll 1
    for (int l = 0; l < LC; ++l) {
      float xv = bf2f(xp[(size_t)l * DI]);
      float a = bde;
#pragma unroll
      for (int r = 0; r < RK; ++r) a = fmaf(wdt[r], sBC[l][r], a);
      float d = fmaxf(a, 0.f) + __logf(1.f + __expf(-fabsf(a)));
      T += d;
      Tp[(size_t)l * DI] = f2h_bits(T);
      float w = d * xv;
      float y = xv * dpe;
#pragma unroll
      for (int s = 0; s < NS; ++s) {
        float q = __expf(d * Aes[s]);
        float hk = fmaf(q, h2[s >> 1][s & 1], w * sBC[l][8 + s]);
        h2[s >> 1][s & 1] = hk;
        y = fmaf(hk, sBC[l][24 + s], y);
      }
      yo[(size_t)l * 576] = f2bf(y);
    }
  }
  float* ep = EA + (((size_t)g * NC + c) * DI + e) * NS;
#pragma unroll
  for (int s = 0; s < NS; s += 4)
    *(float4*)&ep[s] = make_float4(h2[s>>1][0], h2[s>>1][1], h2[(s>>1)+1][0], h2[(s>>1)+1][1]);
}

// inter-chunk combine; q computed from chunk-end T.
// Hin aliases EA (group loads precede group stores).
__global__ __launch_bounds__(256) void k_scanB(const unsigned short* __restrict__ Tb,
    const float* __restrict__ A_log, const float* EA, float* Hin) {
  int idx = blockIdx.x * blockDim.x + threadIdx.x;
  if (idx >= GG * DI * NS) return;
  int g = idx / (DI * NS); int rem = idx - g * (DI * NS);
  int e = rem >> 4, s = rem & 15;
  float Aes = -__expf(A_log[e * NS + s]);
  size_t stride = (size_t)DI * NS;
  size_t b0 = (size_t)g * NC * stride + rem;
  const unsigned short* Tpe = Tb + ((size_t)g * S + (LC - 1)) * DI + e;
  float h = 0.f;
  for (int c0 = 0; c0 < NC; c0 += 8) {
    float t8[8], e8[8];
#pragma unroll
    for (int j = 0; j < 8; ++j) {
      t8[j] = h2f_bits(Tpe[(size_t)(c0 + j) * LC * DI]);
      e8[j] = EA[b0 + (size_t)(c0 + j) * stride];
    }
    float q8[8];
#pragma unroll
    for (int j = 0; j < 8; ++j) q8[j] = __expf(Aes * t8[j]);
#pragma unroll
    for (int j = 0; j < 8; ++j) {
      size_t ix = b0 + (size_t)(c0 + j) * stride;
      Hin[ix] = h;
      h = fmaf(q8[j], h, e8[j]);
    }
  }
}

// ======== scanC2: correction pass y += C * R^(s+1) * h_in ================
__global__ __launch_bounds__(192) void k_scanC2(const unsigned short* __restrict__ Tb,
    const float* __restrict__ xdbl, const float* __restrict__ A_log,
    const float* __restrict__ Hin, unsigned short* __restrict__ ygb) {
  __shared__ float sC[LC][16];
  int c = blockIdx.x, g = blockIdx.y;
  int tid = threadIdx.x;
  int e = tid;
  {
    const float* src = xdbl + ((size_t)g * S + c * LC) * ND + RK + 16;
    for (int i = tid; i < LC * 16; i += 192) {
      int row = i >> 4, col = i & 15;
      sC[row][col] = src[(size_t)row * ND + col];
    }
  }
  float base = -__expf(A_log[e * NS]);
  bool fast = true;
#pragma unroll
  for (int s = 1; s < NS; ++s) {
    float aes = -__expf(A_log[e * NS + s]);
    fast = fast && (fabsf(aes / base - (float)(s + 1)) < 1e-3f);
  }
  const float* hp = Hin + (((size_t)g * NC + c) * DI + e) * NS;
  float4 hv0 = *(const float4*)(hp + 0);
  float4 hv1 = *(const float4*)(hp + 4);
  float4 hv2 = *(const float4*)(hp + 8);
  float4 hv3 = *(const float4*)(hp + 12);
  f32x2 hin[8] = {{hv0.x, hv0.y}, {hv0.z, hv0.w}, {hv1.x, hv1.y}, {hv1.z, hv1.w},
                  {hv2.x, hv2.y}, {hv2.z, hv2.w}, {hv3.x, hv3.y}, {hv3.z, hv3.w}};
  float hmag = fabsf(hv0.x) + fabsf(hv0.y) + fabsf(hv0.z) + fabsf(hv0.w) +
               fabsf(hv1.x) + fabsf(hv1.y) + fabsf(hv1.z) + fabsf(hv1.w) +
               fabsf(hv2.x) + fabsf(hv2.y) + fabsf(hv2.z) + fabsf(hv2.w) +
               fabsf(hv3.x) + fabsf(hv3.y) + fabsf(hv3.z) + fabsf(hv3.w);
  size_t sbase = ((size_t)g * S + c * LC) * DI + e;
  const unsigned short* Tp = Tb + sbase;
  int b = g / 3, dir = g - (g / 3) * 3;
  unsigned short* yo = ygb + ((size_t)b * S + c * LC) * 576 + dir * DI + e;
  __syncthreads();
  if (__builtin_amdgcn_ballot_w64(hmag != 0.f) == 0ull) return;
  if (fast) {
    unsigned short tb2[2][8], yb[2][8];
#pragma unroll
    for (int j = 0; j < 8; ++j) {
      tb2[0][j] = Tp[(size_t)j * DI];
      yb[0][j] = yo[(size_t)j * 576];
    }
#pragma unroll
    for (int blk = 0; blk < 5; ++blk) {
      int cb = blk & 1, nb = cb ^ 1;
      if (blk < 4) {
#pragma unroll
        for (int j = 0; j < 8; ++j) {
          tb2[nb][j] = Tp[(size_t)(blk * 8 + 8 + j) * DI];
          yb[nb][j] = yo[(size_t)(blk * 8 + 8 + j) * 576];
        }
      }
#pragma unroll
      for (int j = 0; j < 8; ++j) {
        int l = blk * 8 + j;
        float T = h2f_bits(tb2[cb][j]);
        float R = __expf(base * T);
        float R2 = R * R, R4 = R2 * R2, R8 = R4 * R4;
        f32x2 R2v = {R2, R2}, R4v = {R4, R4}, R8v = {R8, R8};
        f32x2 q0 = {R, R2};
        f32x2 q1 = q0 * R2v, q2 = q0 * R4v, q3 = q1 * R4v;
        f32x2 q4 = q0 * R8v, q5 = q1 * R8v, q6 = q2 * R8v, q7 = q3 * R8v;
        float4 Ca = *(const float4*)&sC[l][0];
        float4 Cb2 = *(const float4*)&sC[l][4];
        float4 Cc = *(const float4*)&sC[l][8];
        float4 Cd = *(const float4*)&sC[l][12];
        f32x2 ca = (hin[0] * q0) * (f32x2){Ca.x, Ca.y};
        ca += (hin[1] * q1) * (f32x2){Ca.z, Ca.w};
        ca += (hin[2] * q2) * (f32x2){Cb2.x, Cb2.y};
        ca += (hin[3] * q3) * (f32x2){Cb2.z, Cb2.w};
        ca += (hin[4] * q4) * (f32x2){Cc.x, Cc.y};
        ca += (hin[5] * q5) * (f32x2){Cc.z, Cc.w};
        ca += (hin[6] * q6) * (f32x2){Cd.x, Cd.y};
        ca += (hin[7] * q7) * (f32x2){Cd.z, Cd.w};
        float y = bf2f(yb[cb][j]) + ca[0] + ca[1];
        yo[(size_t)l * 576] = f2bf(y);
      }
    }
  } else {
    float Aes[NS];
#pragma unroll
    for (int s = 0; s < NS; ++s) Aes[s] = -__expf(A_log[e * NS + s]);
#pragma unroll 1
    for (int l = 0; l < LC; ++l) {
      float T = h2f_bits(Tp[(size_t)l * DI]);
      float y = bf2f(yo[(size_t)l * 576]);
#pragma unroll
      for (int s = 0; s < NS; ++s) {
        float W = __expf(Aes[s] * T);
        y = fmaf(hin[s >> 1][s & 1] * W, sC[l][s], y);
      }
      yo[(size_t)l * 576] = f2bf(y);
    }
  }
}

// ---------------- fold Wout into proj_w: Mcat[o, dir*192+e] --------------
__global__ __launch_bounds__(256) void k_foldW(const float* __restrict__ proj_w,
    const float* __restrict__ Wout, float* __restrict__ Mcat) {
  int t = blockIdx.x * blockDim.x + threadIdx.x;
  if (t >= CC * 576) return;
  int o = t / 576; int j = t - o * 576; int dir = j / DI; int e = j - dir * DI;
  float a = 0.f;
  for (int c2 = 0; c2 < CC; ++c2)
    a = fmaf(proj_w[o * 288 + dir * CC + c2], Wout[c2 * DI + e], a);
  Mcat[t] = a;
}

extern "C" void kernel_launch(void* const* d_in, const int* in_sizes, int n_in,
                              void* d_out, int out_size, void* d_ws, size_t ws_size,
                              hipStream_t stream) {
  const float* x      = (const float*)d_in[0];
  const float* ln_w   = (const float*)d_in[1];
  const float* ln_b   = (const float*)d_in[2];
  const float* mln_w  = (const float*)d_in[3];
  const float* mln_b  = (const float*)d_in[4];
  const float* Win    = (const float*)d_in[5];
  const float* conv_w = (const float*)d_in[6];
  const float* conv_b = (const float*)d_in[7];
  const float* Wx     = (const float*)d_in[8];
  const float* Wdt    = (const float*)d_in[9];
  const float* bdt    = (const float*)d_in[10];
  const float* A_log  = (const float*)d_in[11];
  const float* Dp     = (const float*)d_in[12];
  const float* Wout   = (const float*)d_in[13];
  const float* proj_w = (const float*)d_in[14];
  const float* proj_b = (const float*)d_in[15];
  const float* fc1_w  = (const float*)d_in[16];
  const float* fc1_b  = (const float*)d_in[17];
  const float* fc2_w  = (const float*)d_in[18];
  const float* fc2_b  = (const float*)d_in[19];

  float* ws = (float*)d_ws;
  size_t off = 0;
  float* ores = ws + off; off += (size_t)BB * S * CC;        // f32
  float* XZf  = ws + off; off += (size_t)BB * S * 384 / 2;   // bf16 (+h1 alias)
  float* xcf  = ws + off; off += (size_t)GG * S * DI / 2;    // bf16
  float* xdbl = ws + off; off += (size_t)GG * S * ND;        // f32
  float* Tf   = ws + off; off += (size_t)GG * S * DI / 2;    // fp16
  float* EA   = ws + off; off += (size_t)GG * NC * DI * NS;  // f32
  float* yg   = ws + off; off += (size_t)BB * S * 576 / 2;   // bf16
  float* Mcat = ws + off; off += (size_t)CC * 576;
  if (ws_size < off * sizeof(float)) return;                 // ~88 MB; guard
  float* Hin  = EA;    // in-place combine (group loads precede stores)
  unsigned short* XZb = (unsigned short*)XZf;
  unsigned short* xcb = (unsigned short*)xcf;
  unsigned short* Tb  = (unsigned short*)Tf;
  unsigned short* ygb = (unsigned short*)yg;
  unsigned short* h1  = (unsigned short*)XZf;

  k_lnmfma<0, true, true><<<dim3(BB * S / 64, 4), 256, 0, stream>>>(
      x, ln_w, ln_b, mln_w, mln_b, Win, nullptr, XZb, BB * S, 384);
  k_conv<<<(GG * S * 48 + 255) / 256, 256, 0, stream>>>(XZb, conv_w, conv_b, xcb);
  k_mfma<0, false, false, false, false, true>
      <<<dim3(GG * S / 64, 1), 256, 0, stream>>>(
      xcb, Wx, nullptr, nullptr, nullptr, xdbl, GG * S, ND, DI);
  k_scanA2<<<dim3(NC, GG), 192, 0, stream>>>(
      xcb, xdbl, Wdt, bdt, A_log, Dp, EA, Tb, ygb);
  k_scanB<<<(GG * DI * NS + 255) / 256, 256, 0, stream>>>(Tb, A_log, EA, Hin);
  k_scanC2<<<dim3(NC, GG), 192, 0, stream>>>(
      Tb, xdbl, A_log, Hin, ygb);
  k_foldW<<<(CC * 576 + 255) / 256, 256, 0, stream>>>(proj_w, Wout, Mcat);
  k_mfma<0, true, true, true, true, true>
      <<<dim3(BB * S / 64, 1), 256, 0, stream>>>(
      ygb, Mcat, proj_b, x, XZb, ores, BB * S, CC, 576);
  k_lnmfma<1, false, true><<<dim3(BB * S / 64, 4), 256, 0, stream>>>(
      ores, ln_w, ln_b, nullptr, nullptr, fc1_w, fc1_b, h1, BB * S, 384);
  k_mfma<0, true, true, true, false, true>
      <<<dim3(BB * S / 64, 1), 256, 0, stream>>>(
      h1, fc2_w, fc2_b, ores, nullptr, (float*)d_out, BB * S, CC, 384);
}